// Round 3
// baseline (415.956 us; speedup 1.0000x reference)
//
#include <hip/hip_runtime.h>
#include <limits.h>

#pragma clang fp contract(off)

#define NB 512
#define NC 151
#define KDIM 4096
#define KS 8
#define KCH (KDIM/KS)      // 512
#define GRB 16             // gemm rows per block
#define PST 152            // padded row stride (floats), 16B-aligned rows
#define NK 64              // commits per round (batch)
#define NL 16              // cached top-list depth per row
#define NMS_TH 0.3f

typedef unsigned long long ull;

// exact reference IoU arithmetic (fp contract off file-wide)
__device__ __forceinline__ bool overlap_ge(const float4& c, const float4& o) {
  float areaC = (c.z - c.x + 1.0f) * (c.w - c.y + 1.0f);
  float areaJ = (o.z - o.x + 1.0f) * (o.w - o.y + 1.0f);
  float iw = fminf(c.z, o.z) - fmaxf(c.x, o.x) + 1.0f;
  float ih = fminf(c.w, o.w) - fmaxf(c.y, o.y) + 1.0f;
  iw = fmaxf(iw, 0.0f); ih = fmaxf(ih, 0.0f);
  float inter = iw * ih;
  float uni = areaC + areaJ - inter;
  return inter / uni >= NMS_TH;
}

__device__ __forceinline__ bool mbit(const unsigned m[5], int c) {
  bool r = false;
#pragma unroll
  for (int k = 0; k < 5; ++k) r = (k == (c >> 5)) ? (((m[k] >> (c & 31)) & 1u) != 0) : r;
  return r;
}

// 64-bit shuffle-xor across the full wave64
__device__ __forceinline__ ull shflx_u64(ull v, int m) {
  int lo = (int)(unsigned)(v & 0xFFFFFFFFull);
  int hi = (int)(unsigned)(v >> 32);
  lo = __shfl_xor(lo, m, 64);
  hi = __shfl_xor(hi, m, 64);
  return ((ull)(unsigned)hi << 32) | (unsigned)lo;
}

__device__ __forceinline__ ull readlane_u64(ull v, int t) {
  int lo = __builtin_amdgcn_readlane((int)(unsigned)(v & 0xFFFFFFFFull), t);
  int hi = __builtin_amdgcn_readlane((int)(unsigned)(v >> 32), t);
  return ((ull)(unsigned)hi << 32) | (unsigned)lo;
}

// ---------------- kernel 1: fused GEMM split-K partials + boxes transpose ----------------
#define TPB_GEMM 256
#define NTR ((NB * NC + 191) / 192)   // 403
__global__ __launch_bounds__(192) void gemm_fused(
    const float* __restrict__ A, const float* __restrict__ W,
    const float* __restrict__ boxes, float* __restrict__ part, float* __restrict__ bt)
{
  if (blockIdx.x >= TPB_GEMM) {
    int i = (blockIdx.x - TPB_GEMM) * 192 + threadIdx.x;
    if (i < NB * NC) {
      int r = i / NC, c = i - r * NC;
      float4 v = *(const float4*)(boxes + (size_t)i * 4);      // coalesced read
      *(float4*)(bt + ((size_t)c * NB + r) * 4) = v;           // scattered write (once)
    }
    return;
  }
  __shared__ float sA[GRB * KCH];  // 32 KB
  int rb = blockIdx.x >> 3, ks = blockIdx.x & 7;
  const float* Ab = A + (size_t)rb * GRB * KDIM + (size_t)ks * KCH;
  for (int i = threadIdx.x; i < GRB * (KCH / 4); i += 192) {
    int r = i >> 7;            // KCH/4 = 128
    int k4 = i & 127;
    *(float4*)(sA + r * KCH + k4 * 4) = *(const float4*)(Ab + (size_t)r * KDIM + k4 * 4);
  }
  __syncthreads();
  int c = threadIdx.x;
  if (c < NC) {
    const float* wp = W + (size_t)ks * KCH * NC + c;
    float acc[GRB];
#pragma unroll
    for (int r = 0; r < GRB; ++r) acc[r] = 0.f;
    float w0 = wp[0], w1 = wp[NC], w2 = wp[2 * NC], w3 = wp[3 * NC];
    for (int k4 = 0; k4 < KCH / 4; ++k4) {
      int kn = (k4 + 1 < KCH / 4) ? (k4 + 1) : k4;     // clamp: re-read last (no OOB)
      const float* q = wp + (size_t)(4 * kn) * NC;
      float n0 = q[0], n1 = q[NC], n2 = q[2 * NC], n3 = q[3 * NC];
#pragma unroll
      for (int r = 0; r < GRB; ++r) {
        float4 a = *(const float4*)(sA + r * KCH + k4 * 4);  // broadcast read
        acc[r] = fmaf(a.x, w0, acc[r]);
        acc[r] = fmaf(a.y, w1, acc[r]);
        acc[r] = fmaf(a.z, w2, acc[r]);
        acc[r] = fmaf(a.w, w3, acc[r]);
      }
      w0 = n0; w1 = n1; w2 = n2; w3 = n3;
    }
    float* o = part + ((size_t)ks * NB + (size_t)rb * GRB) * PST + c;
#pragma unroll
    for (int r = 0; r < GRB; ++r) o[(size_t)r * PST] = acc[r];
  }
}

// ---------------- kernel 2: reduce + obj_dists + softmax probs + top-16 list ----------------
__global__ __launch_bounds__(64) void prep_kernel(
    const float* __restrict__ part, const float* __restrict__ bias,
    float* __restrict__ out, float* __restrict__ lp, float* __restrict__ tl)
{
  int j = blockIdx.x * 64 + threadIdx.x;
  if (j >= NB) return;
  float* pr = lp + (size_t)j * PST;
  float* orow = out + (size_t)j * NC;

  float m_ = -3.4e38f;
  for (int c4 = 0; c4 < PST / 4; ++c4) {
    float x0 = 0.f, x1 = 0.f, x2 = 0.f, x3 = 0.f;
#pragma unroll
    for (int ks = 0; ks < KS; ++ks) {
      const float4 v = *(const float4*)(part + ((size_t)ks * NB + j) * PST + c4 * 4);
      x0 += v.x; x1 += v.y; x2 += v.z; x3 += v.w;
    }
    int c = c4 * 4;
    x0 += bias[c];
    if (c + 1 < NC) x1 += bias[c + 1];
    if (c + 2 < NC) x2 += bias[c + 2];
    if (c + 3 < NC) x3 += bias[c + 3];
    float4 st; st.x = x0; st.y = (c + 1 < NC) ? x1 : -3.4e38f;
    st.z = (c + 2 < NC) ? x2 : -3.4e38f; st.w = (c + 3 < NC) ? x3 : -3.4e38f;
    *(float4*)(pr + c4 * 4) = st;
    orow[c] = x0;
    if (c + 1 < NC) orow[c + 1] = x1;
    if (c + 2 < NC) orow[c + 2] = x2;
    if (c + 3 < NC) orow[c + 3] = x3;
    m_ = fmaxf(m_, st.x); m_ = fmaxf(m_, st.y);
    m_ = fmaxf(m_, st.z); m_ = fmaxf(m_, st.w);
  }
  float s_ = 0.f;
  for (int c4 = 0; c4 < PST / 4; ++c4) {
    float4 v = *(const float4*)(pr + c4 * 4);
    s_ += expf(v.x - m_); s_ += expf(v.y - m_);
    s_ += expf(v.z - m_); s_ += expf(v.w - m_);    // pad: exp(-huge)=0
  }
  float lv[NL]; int lc[NL];
#pragma unroll
  for (int t = 0; t < NL; ++t) { lv[t] = -3.4e38f; lc[t] = 0; }
  for (int c4 = 0; c4 < PST / 4; ++c4) {
    float4 v = *(const float4*)(pr + c4 * 4);
    int c = c4 * 4;
    float p0 = (c == 0) ? 0.f : expf(v.x - m_) / s_;
    float p1 = expf(v.y - m_) / s_;
    float p2 = expf(v.z - m_) / s_;
    float p3 = expf(v.w - m_) / s_;
    float4 st; st.x = p0; st.y = p1; st.z = p2; st.w = p3;   // pad -> 0
    *(float4*)(pr + c4 * 4) = st;
#pragma unroll
    for (int u = 0; u < 4; ++u) {
      float pv = (u == 0) ? p0 : (u == 1) ? p1 : (u == 2) ? p2 : p3;
      int cc = c + u;
      if (pv > 0.f && pv > lv[NL - 1]) {
        lv[NL - 1] = pv; lc[NL - 1] = cc;
#pragma unroll
        for (int q = NL - 1; q > 0; --q) {
          if (lv[q] > lv[q - 1]) {
            float tv = lv[q]; lv[q] = lv[q - 1]; lv[q - 1] = tv;
            int tc = lc[q]; lc[q] = lc[q - 1]; lc[q - 1] = tc;
          }
        }
      }
    }
  }
  float* tr = tl + (size_t)j * (2 * NL);
#pragma unroll
  for (int t = 0; t < NL; ++t) { tr[t] = lv[t]; tr[NL + t] = __int_as_float(lc[t]); }
}

// fallback gemm (ws too small)
__global__ __launch_bounds__(192) void gemm_full(
    const float* __restrict__ A, const float* __restrict__ W,
    const float* __restrict__ bias, float* __restrict__ out)
{
  int c = threadIdx.x;
  int r0 = blockIdx.x * 4;
  if (c >= NC) return;
  const float* a = A + (size_t)r0 * KDIM;
  const float* wp = W + c;
  float a0 = 0.f, a1 = 0.f, a2 = 0.f, a3 = 0.f;
#pragma unroll 8
  for (int k = 0; k < KDIM; ++k) {
    float w = wp[(size_t)k * NC];
    a0 = fmaf(a[k],            w, a0);
    a1 = fmaf(a[k + KDIM],     w, a1);
    a2 = fmaf(a[k + 2 * KDIM], w, a2);
    a3 = fmaf(a[k + 3 * KDIM], w, a3);
  }
  float bb = bias[c];
  out[(size_t)(r0 + 0) * NC + c] = a0 + bb;
  out[(size_t)(r0 + 1) * NC + c] = a1 + bb;
  out[(size_t)(r0 + 2) * NC + c] = a2 + bb;
  out[(size_t)(r0 + 3) * NC + c] = a3 + bb;
}

// ---------------- Multi-commit greedy NMS decode (K=64 + scalar endgame) ----------------
// cand key: (orderable(value) << 32) | (0xFFFFFFFF - flatidx) — u64 order ==
// (value desc, flatidx asc), exactly the reference argmax tie-break. Keys unique.
// Bulk round: per-wave bitonic sort-64 desc (21 shfl) -> 3-level LDS merge tree
// keeping exact top-64 (Batcher max-trick) -> conflict mask (class-first pair
// checks) -> uniform prefix-validity chain -> apply p commits.
// Endgame: once the chain stops on a value<=0 candidate (okm gate), ALL remaining
// scores everywhere are <=0 (sorted + monotone updates), and each row's state is
// a single scalar {0.0@argcls | -1@0} already maintained by the recompute logic.
// Remaining commits = block argmax-reduce (6 shfl + 8-entry LDS combine,
// 2 barriers) + single-commit apply, ~10x cheaper than a sort round.
// Probes: bulk = 2 fully-conflicted LDS reads (62 cnt/round), endgame = 1 read
// (31 cnt/iter) -> SQ_LDS_BANK_CONFLICT ≈ 62*bulk + 31*eg (round-count decode).
template <bool FAST>
__global__ __launch_bounds__(512) void decode_kernel(
    const float* __restrict__ lp, const float* __restrict__ tl,
    const float* __restrict__ boxes /* FAST: bt [NC][NB][4]; else raw */,
    float* __restrict__ commits)
{
  __shared__ ull bufA[NB];                 // 4 KB
  __shared__ ull bufB[NB];                 // 4 KB
  __shared__ __align__(16) int swin[NK];   // packed (row<<8)|cls
  __shared__ ull smask[NK];
  __shared__ ull sred[8];
  const int j = threadIdx.x;
  const int lane = j & 63;
  const int w = j >> 6;

  float lv[NL]; int lc[NL];
  float m_ = 0.f, s_ = 1.f;
  const float* xr = FAST ? (lp + (size_t)j * PST) : (lp + (size_t)j * NC);

  if (FAST) {
    const float4* tl4 = (const float4*)(tl + (size_t)j * (2 * NL));
#pragma unroll
    for (int q = 0; q < NL / 4; ++q) {
      float4 v = tl4[q];
      lv[4 * q] = v.x; lv[4 * q + 1] = v.y; lv[4 * q + 2] = v.z; lv[4 * q + 3] = v.w;
    }
#pragma unroll
    for (int q = 0; q < NL / 4; ++q) {
      float4 v = tl4[NL / 4 + q];
      lc[4 * q] = __float_as_int(v.x); lc[4 * q + 1] = __float_as_int(v.y);
      lc[4 * q + 2] = __float_as_int(v.z); lc[4 * q + 3] = __float_as_int(v.w);
    }
  } else {
#pragma unroll
    for (int t = 0; t < NL; ++t) { lv[t] = -3.4e38f; lc[t] = 0; }
    m_ = xr[0];
    for (int c = 1; c < NC; ++c) m_ = fmaxf(m_, xr[c]);
    s_ = 0.f;
    for (int c = 0; c < NC; ++c) s_ += expf(xr[c] - m_);
    for (int c = 1; c < NC; ++c) {
      float v = expf(xr[c] - m_) / s_;
      if (v > lv[NL - 1]) {
        lv[NL - 1] = v; lc[NL - 1] = c;
#pragma unroll
        for (int q = NL - 1; q > 0; --q) {
          if (lv[q] > lv[q - 1]) {
            float tv = lv[q]; lv[q] = lv[q - 1]; lv[q - 1] = tv;
            int tc = lc[q]; lc[q] = lc[q - 1]; lc[q - 1] = tc;
          }
        }
      }
    }
  }

  float rowmax; int argcls; bool zstuck = false;
  if (lv[0] > 0.f) { rowmax = lv[0]; argcls = lc[0]; }
  else { rowmax = 0.f; argcls = 0; zstuck = true; }

  unsigned mask[5] = {0, 0, 0, 0, 0};
  bool retired = false;
  int post_min = INT_MAX;
  int commitcls = 0;
  int committed = 0;

  while (committed < NB) {
    ull key;
    {
      unsigned u = __float_as_uint(rowmax);
      u ^= (u & 0x80000000u) ? 0xFFFFFFFFu : 0x80000000u;   // orderable encoding
      key = ((ull)u << 32) | (unsigned)(0xFFFFFFFFu - (unsigned)(j * NC + argcls));
    }

    // 6-step descending bitonic merge of a bitonic 64-seq (in-wave)
    auto mergeDesc = [&]() {
#pragma unroll
      for (int dd = 32; dd >= 1; dd >>= 1) {
        ull o = shflx_u64(key, dd);
        bool km = ((lane & dd) == 0);
        ull mx = key > o ? key : o, mn = key > o ? o : key;
        key = km ? mx : mn;
      }
    };

    // ---- per-wave bitonic sort-64 desc (21 steps) ----
#pragma unroll
    for (int kk = 2; kk <= 32; kk <<= 1) {
#pragma unroll
      for (int dd = kk >> 1; dd >= 1; dd >>= 1) {
        ull o = shflx_u64(key, dd);
        bool km = (((lane & dd) == 0) == ((lane & kk) == 0));
        ull mx = key > o ? key : o, mn = key > o ? o : key;
        key = km ? mx : mn;
      }
    }
    mergeDesc();

    bufA[j] = key;
    __syncthreads();   // B1

    // ---- level 1: waves 0-3 merge sorted-64 pairs, keep top-64 ----
    if (w < 4) {
      ull a = bufA[w * 128 + lane];
      ull b = bufA[w * 128 + 64 + (63 - lane)];
      key = a > b ? a : b;           // exact top-64 of the pair (bitonic)
      mergeDesc();
      bufB[w * 64 + lane] = key;
    } else if (w == 7) {
      // rounds probe: 2 fully-conflicted LDS reads -> ~62 conflict counts/round
      volatile int* pb = (volatile int*)bufA;
      int t0 = pb[(lane & 31) * 32];
      int t1 = pb[(lane & 31) * 32 + 1];
      asm volatile("" :: "v"(t0), "v"(t1));
    }
    __syncthreads();   // B2

    // ---- level 2: waves 0-1 ----
    if (w < 2) {
      ull a = bufB[w * 128 + lane];
      ull b = bufB[w * 128 + 64 + (63 - lane)];
      key = a > b ? a : b;
      mergeDesc();
      bufA[w * 64 + lane] = key;
    }
    __syncthreads();   // B3

    // ---- level 3: wave 0 -> exact global top-64 sorted desc; publish ----
    if (w == 0) {
      ull a = bufA[lane];
      ull b = bufA[64 + (63 - lane)];
      key = a > b ? a : b;
      mergeDesc();
      bufB[lane] = key;
      unsigned f = 0xFFFFFFFFu - (unsigned)key;
      int row = (int)(f / (unsigned)NC);
      int cls = (int)(f - (unsigned)row * (unsigned)NC);
      swin[lane] = (row << 8) | cls;
      smask[lane] = 0ull;
    }
    __syncthreads();   // B4

    // ---- conflict detection: all 64x64 (s<t) pairs, 8 per thread ----
    {
      int t = j >> 3, sb = (j & 7) * 8;
      int pT = swin[t];
      int cT = pT & 255, rT = pT >> 8;
      int4 sA4 = *(const int4*)&swin[sb];
      int4 sB4 = *(const int4*)&swin[sb + 4];
      int ss[8] = {sA4.x, sA4.y, sA4.z, sA4.w, sB4.x, sB4.y, sB4.z, sB4.w};
      ull myc = 0ull;
#pragma unroll
      for (int u = 0; u < 8; ++u) {
        int s = sb + u;
        if (s < t && (ss[u] & 255) == cT) {      // rare (~1/150 per pair)
          int rS = ss[u] >> 8;
          float4 bs, btx;
          if (FAST) {
            bs  = *(const float4*)(boxes + ((size_t)cT * NB + rS) * 4);
            btx = *(const float4*)(boxes + ((size_t)cT * NB + rT) * 4);
          } else {
            bs  = *(const float4*)(boxes + ((size_t)rS * NC + cT) * 4);
            btx = *(const float4*)(boxes + ((size_t)rT * NC + cT) * 4);
          }
          if (overlap_ge(bs, btx)) myc |= (1ull << s);
        }
      }
      if (myc) atomicOr(&smask[t], myc);
    }
    __syncthreads();   // B5

    // ---- prefix-validity chain (per-wave, identical result everywhere) ----
    int p; bool egflag;
    {
      int kmax = NB - committed; if (kmax > NK) kmax = NK;
      ull kv = bufB[lane];       // candidate 'lane' key
      ull sm = smask[lane];
      ull okm = __ballot((lane < kmax) &&
                         ((unsigned)(kv >> 32) > 0x80000000u));  // orderable(0.0)=0x80000000
      ull valid = 1ull; p = 1;   // t=0 always commits (reference: argmax regardless of value)
#pragma unroll
      for (int t = 1; t < NK; ++t) {
        ull cm = readlane_u64(sm, t);
        bool ok = (p == t) && ((okm >> t) & 1ull) && ((cm & valid) == 0ull);
        if (ok) { valid |= (1ull << t); p = t + 1; }
      }
      // okm-stop (not conflict-stop) => candidate p value <= 0 => no positive
      // scores remain anywhere (sorted batch + monotone updates) => endgame.
      egflag = (p < NK) && !((okm >> p) & 1ull);
    }

    // ---- all threads: apply the p commits in order, rolled groups of 8 ----
#pragma unroll 1
    for (int g = 0; g * 8 < p; ++g) {
      int rows_[8], cls_[8];
      float4 cb[8], ob[8];
#pragma unroll
      for (int u = 0; u < 8; ++u) {
        int t = g * 8 + u;
        int pkv = __builtin_amdgcn_readfirstlane(swin[t]);   // uniform scalar
        rows_[u] = pkv >> 8; cls_[u] = pkv & 255;
        if (t < p) {
          if (FAST) {
            const float* btc = boxes + (size_t)cls_[u] * NB * 4;
            cb[u] = *(const float4*)(btc + (size_t)rows_[u] * 4);  // s_load (uniform)
            ob[u] = *(const float4*)(btc + (size_t)j * 4);         // lane-dense
          } else {
            cb[u] = *(const float4*)(boxes + ((size_t)rows_[u] * NC + cls_[u]) * 4);
            ob[u] = *(const float4*)(boxes + ((size_t)j * NC + cls_[u]) * 4);
          }
        }
      }
#pragma unroll
      for (int u = 0; u < 8; ++u) {
        int t = g * 8 + u;
        if (t < p) {
          if (j == rows_[u]) {
            // commit: col update overwritten by row := -1 (reference order)
            retired = true; commitcls = cls_[u]; post_min = INT_MAX;
          } else if (overlap_ge(cb[u], ob[u])) {
            if (retired) {
              post_min = (cls_[u] < post_min) ? cls_[u] : post_min;  // resurrect -1 -> 0.0
            } else {
              int c = cls_[u];
#pragma unroll
              for (int k5b = 0; k5b < 5; ++k5b) if (k5b == (c >> 5)) mask[k5b] |= (1u << (c & 31));
            }
          }
        }
      }
    }

    // ---- event-driven candidate recompute ----
    if (retired) {
      rowmax = (post_min != INT_MAX) ? 0.0f : -1.0f;
      argcls = (post_min != INT_MAX) ? post_min : 0;
    } else if (!zstuck && mbit(mask, argcls)) {
      // my class was just suppressed: scan cached top-16
      bool found = false;
#pragma unroll
      for (int t = 0; t < NL; ++t) {
        if (!found && lv[t] > 0.f && !mbit(mask, lc[t])) {
          rowmax = lv[t]; argcls = lc[t]; found = true;
        }
      }
      if (!found) {
        // cheap max-only rescan over stored probs (FAST) / expf recompute (fallback)
        float bm = -3.4e38f; int ba = 0;
        if (FAST) {
          for (int c4 = 0; c4 < PST / 4; ++c4) {
            float4 v4 = *(const float4*)(xr + c4 * 4);   // probs; class0=0, pad=0
            int c = c4 * 4;
            float vals[4] = {v4.x, v4.y, v4.z, v4.w};
#pragma unroll
            for (int u = 0; u < 4; ++u) {
              int cc = c + u;
              float v = mbit(mask, cc) ? 0.f : vals[u];
              if (v > bm) { bm = v; ba = cc; }   // cc=0 (v=0) hits first; pads never exceed
            }
          }
        } else {
          for (int c = 0; c < NC; ++c) {
            float v;
            if (c == 0) v = 0.f;
            else v = mbit(mask, c) ? 0.f : (expf(xr[c] - m_) / s_);
            if (v > bm) { bm = v; ba = c; }
          }
        }
        rowmax = bm; argcls = ba;
        if (!(bm > 0.f)) zstuck = true;   // all-zero row: candidate stable forever
      }
    }
    // zstuck: keep (rowmax=0, argcls) — values never increase for this row

    committed += p;

    // ---- endgame: all remaining scores <= 0; per-row state is one scalar ----
    if (egflag) {
      while (committed < NB) {
        unsigned u = __float_as_uint(rowmax);
        u ^= (u & 0x80000000u) ? 0xFFFFFFFFu : 0x80000000u;
        ull k = ((ull)u << 32) | (unsigned)(0xFFFFFFFFu - (unsigned)(j * NC + argcls));
#pragma unroll
        for (int dd = 32; dd >= 1; dd >>= 1) {
          ull o = shflx_u64(k, dd);
          k = k > o ? k : o;
        }
        __syncthreads();                 // protect sred reuse
        if (lane == 0) sred[w] = k;
        if (w == 7) {
          // endgame probe: 1 fully-conflicted LDS read -> ~31 counts/iter
          volatile int* pb = (volatile int*)bufA;
          int t0 = pb[(lane & 31) * 32];
          asm volatile("" :: "v"(t0));
        }
        __syncthreads();
        ull g = sred[0];
#pragma unroll
        for (int q = 1; q < 8; ++q) { ull t = sred[q]; g = g > t ? g : t; }
        unsigned f = 0xFFFFFFFFu - (unsigned)g;
        int row = (int)(f / (unsigned)NC);
        int cls = (int)(f - (unsigned)row * (unsigned)NC);
        float4 cb, ob;
        if (FAST) {
          const float* btc = boxes + (size_t)cls * NB * 4;
          cb = *(const float4*)(btc + (size_t)row * 4);
          ob = *(const float4*)(btc + (size_t)j * 4);
        } else {
          cb = *(const float4*)(boxes + ((size_t)row * NC + cls) * 4);
          ob = *(const float4*)(boxes + ((size_t)j * NC + cls) * 4);
        }
        if (j == row) {
          // commit (possibly re-commit): row := -1, reset resurrect state
          retired = true; commitcls = cls; post_min = INT_MAX;
          rowmax = -1.0f; argcls = 0;
        } else if (overlap_ge(cb, ob)) {
          if (retired) {
            post_min = (cls < post_min) ? cls : post_min;   // resurrect -1 -> 0.0 @ min cls
            rowmax = 0.0f; argcls = post_min;
          }
          // live rows here are all-suppressed (0.0 @ class 0): writing another
          // 0.0 entry never changes their argmax (class 0 is flat-min).
        }
        ++committed;
      }
    }
  }

  commits[j] = (float)commitcls;
}

extern "C" void kernel_launch(void* const* d_in, const int* in_sizes, int n_in,
                              void* d_out, int out_size, void* d_ws, size_t ws_size,
                              hipStream_t stream) {
  const float* A     = (const float*)d_in[0];   // obj_fmap [512,4096]
  const float* boxes = (const float*)d_in[1];   // boxes_per_cls [512,151,4]
  const float* W     = (const float*)d_in[2];   // [4096,151]
  const float* bias  = (const float*)d_in[3];   // [151]
  float* out = (float*)d_out;                   // [512*151] obj_dists ++ [512] commits

  const size_t np = (size_t)KS * NB * PST;      // part
  const size_t nl = (size_t)NB * PST;           // lp
  const size_t nt = (size_t)NB * (2 * NL);      // tl
  const size_t nb = (size_t)NC * NB * 4;        // bt
  const size_t need = (np + nl + nt + nb) * 4;

  if (ws_size >= need) {
    float* part = (float*)d_ws;
    float* lp   = part + np;
    float* tl   = lp + nl;
    float* bt   = tl + nt;
    gemm_fused<<<TPB_GEMM + NTR, 192, 0, stream>>>(A, W, boxes, part, bt);
    prep_kernel<<<NB / 64, 64, 0, stream>>>(part, bias, out, lp, tl);
    decode_kernel<true><<<1, NB, 0, stream>>>(lp, tl, bt, out + NB * NC);
  } else {
    gemm_full<<<NB / 4, 192, 0, stream>>>(A, W, bias, out);
    decode_kernel<false><<<1, NB, 0, stream>>>(out, nullptr, boxes, out + NB * NC);
  }
}

// Round 4
// 382.349 us; speedup vs baseline: 1.0879x; 1.0879x over previous
//
#include <hip/hip_runtime.h>
#include <limits.h>

#pragma clang fp contract(off)

#define NB 512
#define NC 151
#define KDIM 4096
#define KS 8
#define KCH (KDIM/KS)      // 512
#define GRB 16             // gemm rows per block
#define PST 152            // padded row stride (floats), 16B-aligned rows
#define NK 64              // commits per round (batch)
#define NL 16              // cached top-list depth per row
#define CMX 16             // per-class log index slots (overflow -> filtered scan)
#define NMS_TH 0.3f

typedef unsigned long long ull;

// exact reference IoU arithmetic (fp contract off file-wide)
__device__ __forceinline__ bool overlap_ge(const float4& c, const float4& o) {
  float areaC = (c.z - c.x + 1.0f) * (c.w - c.y + 1.0f);
  float areaJ = (o.z - o.x + 1.0f) * (o.w - o.y + 1.0f);
  float iw = fminf(c.z, o.z) - fmaxf(c.x, o.x) + 1.0f;
  float ih = fminf(c.w, o.w) - fmaxf(c.y, o.y) + 1.0f;
  iw = fmaxf(iw, 0.0f); ih = fmaxf(ih, 0.0f);
  float inter = iw * ih;
  float uni = areaC + areaJ - inter;
  return inter / uni >= NMS_TH;
}

__device__ __forceinline__ bool mbit(const unsigned m[5], int c) {
  bool r = false;
#pragma unroll
  for (int k = 0; k < 5; ++k) r = (k == (c >> 5)) ? (((m[k] >> (c & 31)) & 1u) != 0) : r;
  return r;
}

// 64-bit shuffle-xor across the full wave64
__device__ __forceinline__ ull shflx_u64(ull v, int m) {
  int lo = (int)(unsigned)(v & 0xFFFFFFFFull);
  int hi = (int)(unsigned)(v >> 32);
  lo = __shfl_xor(lo, m, 64);
  hi = __shfl_xor(hi, m, 64);
  return ((ull)(unsigned)hi << 32) | (unsigned)lo;
}

__device__ __forceinline__ ull readlane_u64(ull v, int t) {
  int lo = __builtin_amdgcn_readlane((int)(unsigned)(v & 0xFFFFFFFFull), t);
  int hi = __builtin_amdgcn_readlane((int)(unsigned)(v >> 32), t);
  return ((ull)(unsigned)hi << 32) | (unsigned)lo;
}

// ---------------- kernel 1: fused GEMM split-K partials + boxes transpose ----------------
#define TPB_GEMM 256
#define NTR ((NB * NC + 191) / 192)   // 403
__global__ __launch_bounds__(192) void gemm_fused(
    const float* __restrict__ A, const float* __restrict__ W,
    const float* __restrict__ boxes, float* __restrict__ part, float* __restrict__ bt)
{
  if (blockIdx.x >= TPB_GEMM) {
    int i = (blockIdx.x - TPB_GEMM) * 192 + threadIdx.x;
    if (i < NB * NC) {
      int r = i / NC, c = i - r * NC;
      float4 v = *(const float4*)(boxes + (size_t)i * 4);      // coalesced read
      *(float4*)(bt + ((size_t)c * NB + r) * 4) = v;           // scattered write (once)
    }
    return;
  }
  __shared__ float sA[GRB * KCH];  // 32 KB
  int rb = blockIdx.x >> 3, ks = blockIdx.x & 7;
  const float* Ab = A + (size_t)rb * GRB * KDIM + (size_t)ks * KCH;
  for (int i = threadIdx.x; i < GRB * (KCH / 4); i += 192) {
    int r = i >> 7;            // KCH/4 = 128
    int k4 = i & 127;
    *(float4*)(sA + r * KCH + k4 * 4) = *(const float4*)(Ab + (size_t)r * KDIM + k4 * 4);
  }
  __syncthreads();
  int c = threadIdx.x;
  if (c < NC) {
    const float* wp = W + (size_t)ks * KCH * NC + c;
    float acc[GRB];
#pragma unroll
    for (int r = 0; r < GRB; ++r) acc[r] = 0.f;
    float w0 = wp[0], w1 = wp[NC], w2 = wp[2 * NC], w3 = wp[3 * NC];
    for (int k4 = 0; k4 < KCH / 4; ++k4) {
      int kn = (k4 + 1 < KCH / 4) ? (k4 + 1) : k4;     // clamp: re-read last (no OOB)
      const float* q = wp + (size_t)(4 * kn) * NC;
      float n0 = q[0], n1 = q[NC], n2 = q[2 * NC], n3 = q[3 * NC];
#pragma unroll
      for (int r = 0; r < GRB; ++r) {
        float4 a = *(const float4*)(sA + r * KCH + k4 * 4);  // broadcast read
        acc[r] = fmaf(a.x, w0, acc[r]);
        acc[r] = fmaf(a.y, w1, acc[r]);
        acc[r] = fmaf(a.z, w2, acc[r]);
        acc[r] = fmaf(a.w, w3, acc[r]);
      }
      w0 = n0; w1 = n1; w2 = n2; w3 = n3;
    }
    float* o = part + ((size_t)ks * NB + (size_t)rb * GRB) * PST + c;
#pragma unroll
    for (int r = 0; r < GRB; ++r) o[(size_t)r * PST] = acc[r];
  }
}

// ---------------- kernel 2: reduce + obj_dists + softmax probs + top-16 list ----------------
__global__ __launch_bounds__(64) void prep_kernel(
    const float* __restrict__ part, const float* __restrict__ bias,
    float* __restrict__ out, float* __restrict__ lp, float* __restrict__ tl)
{
  int j = blockIdx.x * 64 + threadIdx.x;
  if (j >= NB) return;
  float* pr = lp + (size_t)j * PST;
  float* orow = out + (size_t)j * NC;

  float m_ = -3.4e38f;
  for (int c4 = 0; c4 < PST / 4; ++c4) {
    float x0 = 0.f, x1 = 0.f, x2 = 0.f, x3 = 0.f;
#pragma unroll
    for (int ks = 0; ks < KS; ++ks) {
      const float4 v = *(const float4*)(part + ((size_t)ks * NB + j) * PST + c4 * 4);
      x0 += v.x; x1 += v.y; x2 += v.z; x3 += v.w;
    }
    int c = c4 * 4;
    x0 += bias[c];
    if (c + 1 < NC) x1 += bias[c + 1];
    if (c + 2 < NC) x2 += bias[c + 2];
    if (c + 3 < NC) x3 += bias[c + 3];
    float4 st; st.x = x0; st.y = (c + 1 < NC) ? x1 : -3.4e38f;
    st.z = (c + 2 < NC) ? x2 : -3.4e38f; st.w = (c + 3 < NC) ? x3 : -3.4e38f;
    *(float4*)(pr + c4 * 4) = st;
    orow[c] = x0;
    if (c + 1 < NC) orow[c + 1] = x1;
    if (c + 2 < NC) orow[c + 2] = x2;
    if (c + 3 < NC) orow[c + 3] = x3;
    m_ = fmaxf(m_, st.x); m_ = fmaxf(m_, st.y);
    m_ = fmaxf(m_, st.z); m_ = fmaxf(m_, st.w);
  }
  float s_ = 0.f;
  for (int c4 = 0; c4 < PST / 4; ++c4) {
    float4 v = *(const float4*)(pr + c4 * 4);
    s_ += expf(v.x - m_); s_ += expf(v.y - m_);
    s_ += expf(v.z - m_); s_ += expf(v.w - m_);    // pad: exp(-huge)=0
  }
  float lv[NL]; int lc[NL];
#pragma unroll
  for (int t = 0; t < NL; ++t) { lv[t] = -3.4e38f; lc[t] = 0; }
  for (int c4 = 0; c4 < PST / 4; ++c4) {
    float4 v = *(const float4*)(pr + c4 * 4);
    int c = c4 * 4;
    float p0 = (c == 0) ? 0.f : expf(v.x - m_) / s_;
    float p1 = expf(v.y - m_) / s_;
    float p2 = expf(v.z - m_) / s_;
    float p3 = expf(v.w - m_) / s_;
    float4 st; st.x = p0; st.y = p1; st.z = p2; st.w = p3;   // pad -> 0
    *(float4*)(pr + c4 * 4) = st;
#pragma unroll
    for (int u = 0; u < 4; ++u) {
      float pv = (u == 0) ? p0 : (u == 1) ? p1 : (u == 2) ? p2 : p3;
      int cc = c + u;
      if (pv > 0.f && pv > lv[NL - 1]) {
        lv[NL - 1] = pv; lc[NL - 1] = cc;
#pragma unroll
        for (int q = NL - 1; q > 0; --q) {
          if (lv[q] > lv[q - 1]) {
            float tv = lv[q]; lv[q] = lv[q - 1]; lv[q - 1] = tv;
            int tc = lc[q]; lc[q] = lc[q - 1]; lc[q - 1] = tc;
          }
        }
      }
    }
  }
  float* tr = tl + (size_t)j * (2 * NL);
#pragma unroll
  for (int t = 0; t < NL; ++t) { tr[t] = lv[t]; tr[NL + t] = __int_as_float(lc[t]); }
}

// fallback gemm (ws too small)
__global__ __launch_bounds__(192) void gemm_full(
    const float* __restrict__ A, const float* __restrict__ W,
    const float* __restrict__ bias, float* __restrict__ out)
{
  int c = threadIdx.x;
  int r0 = blockIdx.x * 4;
  if (c >= NC) return;
  const float* a = A + (size_t)r0 * KDIM;
  const float* wp = W + c;
  float a0 = 0.f, a1 = 0.f, a2 = 0.f, a3 = 0.f;
#pragma unroll 8
  for (int k = 0; k < KDIM; ++k) {
    float w = wp[(size_t)k * NC];
    a0 = fmaf(a[k],            w, a0);
    a1 = fmaf(a[k + KDIM],     w, a1);
    a2 = fmaf(a[k + 2 * KDIM], w, a2);
    a3 = fmaf(a[k + 3 * KDIM], w, a3);
  }
  float bb = bias[c];
  out[(size_t)(r0 + 0) * NC + c] = a0 + bb;
  out[(size_t)(r0 + 1) * NC + c] = a1 + bb;
  out[(size_t)(r0 + 2) * NC + c] = a2 + bb;
  out[(size_t)(r0 + 3) * NC + c] = a3 + bb;
}

// ---------------- Multi-commit greedy NMS decode (K=64, lazy suppression) ----------------
// cand key: (orderable(value) << 32) | (0xFFFFFFFF - flatidx) — u64 order ==
// (value desc, flatidx asc) == exact reference argmax tie-break. Keys unique.
// Per round: per-wave bitonic sort-64 desc (21 shfl) -> 3-level LDS merge tree
// keeping exact top-64 (Batcher max-trick) -> within-batch conflict mask ->
// uniform prefix-validity chain -> LAZY apply:
//   * commits appended to an LDS log (append order = reference commit order)
//     with a per-class CSR index (CMX slots; overflow -> filtered full scan).
//   * per live thread: p integer compares (j==row_t retire check, cls_t==argcls
//     suppression check); IoU only on the rare class match.
//   * candidate pull validates against the per-class history (== the old eager
//     mask semantics, evaluated on demand).
//   * retired rows propose -1 and defer resurrect state: non-positive proposals
//     can never win while positives exist; if a non-positive ever tops a batch
//     (okm gate incl. position 0), we break to the endgame which reconstructs
//     EXACT per-row state (mask/post_min/retire) by an ordered log scan, then
//     runs the verified single-commit argmax loop.
// Probes: bulk round = 2 single-bank LDS reads (wave7), endgame iter = 1 ->
// SQ_LDS_BANK_CONFLICT == 992 again iff round structure unchanged (8 rounds).
template <bool FAST>
__global__ __launch_bounds__(512) void decode_kernel(
    const float* __restrict__ lp, const float* __restrict__ tl,
    const float* __restrict__ boxes /* FAST: bt [NC][NB][4]; else raw */,
    float* __restrict__ commits)
{
  __shared__ ull bufA[NB];                 // 4 KB
  __shared__ ull bufB[NB];                 // 4 KB
  __shared__ __align__(16) int swin[NK];   // packed (row<<8)|cls
  __shared__ ull smask[NK];
  __shared__ unsigned slog[NB];            // commit log, append order
  __shared__ int cls_cnt[NC];
  __shared__ unsigned short cls_ref[NC][CMX];
  __shared__ ull sred[8];
  const int j = threadIdx.x;
  const int lane = j & 63;
  const int w = j >> 6;

  auto bload = [&](int cls, int row) -> float4 {
    return FAST ? *(const float4*)(boxes + ((size_t)cls * NB + row) * 4)
                : *(const float4*)(boxes + ((size_t)row * NC + cls) * 4);
  };

  if (j < NC) cls_cnt[j] = 0;

  float lv[NL]; int lc[NL];
  float m_ = 0.f, s_ = 1.f;
  const float* xr = FAST ? (lp + (size_t)j * PST) : (lp + (size_t)j * NC);

  if (FAST) {
    const float4* tl4 = (const float4*)(tl + (size_t)j * (2 * NL));
#pragma unroll
    for (int q = 0; q < NL / 4; ++q) {
      float4 v = tl4[q];
      lv[4 * q] = v.x; lv[4 * q + 1] = v.y; lv[4 * q + 2] = v.z; lv[4 * q + 3] = v.w;
    }
#pragma unroll
    for (int q = 0; q < NL / 4; ++q) {
      float4 v = tl4[NL / 4 + q];
      lc[4 * q] = __float_as_int(v.x); lc[4 * q + 1] = __float_as_int(v.y);
      lc[4 * q + 2] = __float_as_int(v.z); lc[4 * q + 3] = __float_as_int(v.w);
    }
  } else {
#pragma unroll
    for (int t = 0; t < NL; ++t) { lv[t] = -3.4e38f; lc[t] = 0; }
    m_ = xr[0];
    for (int c = 1; c < NC; ++c) m_ = fmaxf(m_, xr[c]);
    s_ = 0.f;
    for (int c = 0; c < NC; ++c) s_ += expf(xr[c] - m_);
    for (int c = 1; c < NC; ++c) {
      float v = expf(xr[c] - m_) / s_;
      if (v > lv[NL - 1]) {
        lv[NL - 1] = v; lc[NL - 1] = c;
#pragma unroll
        for (int q = NL - 1; q > 0; --q) {
          if (lv[q] > lv[q - 1]) {
            float tv = lv[q]; lv[q] = lv[q - 1]; lv[q - 1] = tv;
            int tc = lc[q]; lc[q] = lc[q - 1]; lc[q - 1] = tc;
          }
        }
      }
    }
  }

  float rowmax; int argcls; bool zstuck = false;
  if (lv[0] > 0.f) { rowmax = lv[0]; argcls = lc[0]; }
  else { rowmax = 0.f; argcls = 0; zstuck = true; }

  bool retired = false;
  int commitcls = 0;
  int committed = 0;
  int logcnt = 0;
  bool eg = false;

  while (committed < NB) {
    ull key;
    {
      unsigned u = __float_as_uint(rowmax);
      u ^= (u & 0x80000000u) ? 0xFFFFFFFFu : 0x80000000u;   // orderable encoding
      key = ((ull)u << 32) | (unsigned)(0xFFFFFFFFu - (unsigned)(j * NC + argcls));
    }

    // 6-step descending bitonic merge of a bitonic 64-seq (in-wave)
    auto mergeDesc = [&]() {
#pragma unroll
      for (int dd = 32; dd >= 1; dd >>= 1) {
        ull o = shflx_u64(key, dd);
        bool km = ((lane & dd) == 0);
        ull mx = key > o ? key : o, mn = key > o ? o : key;
        key = km ? mx : mn;
      }
    };

    // ---- per-wave bitonic sort-64 desc (21 steps) ----
#pragma unroll
    for (int kk = 2; kk <= 32; kk <<= 1) {
#pragma unroll
      for (int dd = kk >> 1; dd >= 1; dd >>= 1) {
        ull o = shflx_u64(key, dd);
        bool km = (((lane & dd) == 0) == ((lane & kk) == 0));
        ull mx = key > o ? key : o, mn = key > o ? o : key;
        key = km ? mx : mn;
      }
    }
    mergeDesc();

    bufA[j] = key;
    __syncthreads();   // B1

    // ---- level 1: waves 0-3 merge sorted-64 pairs, keep top-64 ----
    if (w < 4) {
      ull a = bufA[w * 128 + lane];
      ull b = bufA[w * 128 + 64 + (63 - lane)];
      key = a > b ? a : b;           // exact top-64 of the pair (bitonic)
      mergeDesc();
      bufB[w * 64 + lane] = key;
    } else if (w == 7) {
      // rounds probe: 2 single-bank LDS reads per bulk round
      volatile int* pb = (volatile int*)bufA;
      int t0 = pb[(lane & 31) * 32];
      int t1 = pb[(lane & 31) * 32 + 1];
      asm volatile("" :: "v"(t0), "v"(t1));
    }
    __syncthreads();   // B2

    // ---- level 2: waves 0-1 ----
    if (w < 2) {
      ull a = bufB[w * 128 + lane];
      ull b = bufB[w * 128 + 64 + (63 - lane)];
      key = a > b ? a : b;
      mergeDesc();
      bufA[w * 64 + lane] = key;
    }
    __syncthreads();   // B3

    // ---- level 3: wave 0 -> exact global top-64 sorted desc; publish ----
    if (w == 0) {
      ull a = bufA[lane];
      ull b = bufA[64 + (63 - lane)];
      key = a > b ? a : b;
      mergeDesc();
      bufB[lane] = key;
      unsigned f = 0xFFFFFFFFu - (unsigned)key;
      int row = (int)(f / (unsigned)NC);
      int cls = (int)(f - (unsigned)row * (unsigned)NC);
      swin[lane] = (row << 8) | cls;
      smask[lane] = 0ull;
    }
    __syncthreads();   // B4

    // ---- conflict detection: all 64x64 (s<t) pairs, 8 per thread ----
    {
      int t = j >> 3, sb = (j & 7) * 8;
      int pT = swin[t];
      int cT = pT & 255, rT = pT >> 8;
      int4 sA4 = *(const int4*)&swin[sb];
      int4 sB4 = *(const int4*)&swin[sb + 4];
      int ss[8] = {sA4.x, sA4.y, sA4.z, sA4.w, sB4.x, sB4.y, sB4.z, sB4.w};
      ull myc = 0ull;
#pragma unroll
      for (int u = 0; u < 8; ++u) {
        int s = sb + u;
        if (s < t && (ss[u] & 255) == cT) {      // rare (~1/150 per pair)
          int rS = ss[u] >> 8;
          float4 bs = bload(cT, rS);
          float4 btx = bload(cT, rT);
          if (overlap_ge(bs, btx)) myc |= (1ull << s);
        }
      }
      if (myc) atomicOr(&smask[t], myc);
    }
    __syncthreads();   // B5

    // ---- prefix-validity chain (per-wave, identical result everywhere) ----
    int p;
    {
      int kmax = NB - committed; if (kmax > NK) kmax = NK;
      ull kv = bufB[lane];       // candidate 'lane' key
      ull sm = smask[lane];
      ull okm = __ballot((lane < kmax) &&
                         ((unsigned)(kv >> 32) > 0x80000000u));  // orderable(0.0)=0x80000000
      if (!(okm & 1ull)) {
        p = 0; eg = true;        // even the batch top is non-positive -> endgame decides
      } else {
        ull valid = 1ull; p = 1;
#pragma unroll
        for (int t = 1; t < NK; ++t) {
          ull cm = readlane_u64(sm, t);
          bool ok = (p == t) && ((okm >> t) & 1ull) && ((cm & valid) == 0ull);
          if (ok) { valid |= (1ull << t); p = t + 1; }
        }
        // okm-stop (not conflict-stop) => all remaining scores <= 0 => endgame
        eg = (p < NK) && !((okm >> p) & 1ull);
      }
    }

    // ---- append commits to the log + per-class index ----
    if (j < p) {
      unsigned e = (unsigned)swin[j];
      slog[logcnt + j] = e;
      int c = (int)(e & 255u);
      int old = atomicAdd(&cls_cnt[c], 1);
      if (old < CMX) cls_ref[c][old] = (unsigned short)(logcnt + j);
    }
    __syncthreads();   // B6: appends visible to pulls

    // ---- lazy apply: p integer compares per thread, IoU only on class match ----
    bool supp = false;
    for (int t = 0; t < p; ++t) {
      int e = __builtin_amdgcn_readfirstlane(swin[t]);   // uniform scalar
      int rt = e >> 8;
      if (j == rt) {
        retired = true; commitcls = e & 255;             // reference commit
      } else if (!retired && !zstuck && !supp && (e & 255) == argcls) {
        float4 cb = bload(e & 255, rt);                  // uniform
        float4 ob = bload(e & 255, j);                   // lane-dense
        if (overlap_ge(cb, ob)) supp = true;
      }
    }

    // ---- event-driven candidate recompute ----
    if (retired) {
      rowmax = -1.0f; argcls = 0;    // resurrect state deferred to endgame (can't win vs positives)
    } else if (supp) {
      // pull next candidate from cache, validated against the FULL commit history
      bool found = false;
#pragma unroll 1
      for (int t = 0; t < NL && !found; ++t) {
        if (!(lv[t] > 0.f)) break;       // sorted desc: no positives left
        int c = lc[t];
        int cnt = cls_cnt[c];
        bool bad = false;
        if (cnt > 0) {
          float4 ob = bload(c, j);
          if (cnt <= CMX) {
            for (int q = 0; q < cnt && !bad; ++q) {
              unsigned e = slog[cls_ref[c][q]];
              float4 cb = bload(c, (int)(e >> 8));
              if (overlap_ge(cb, ob)) bad = true;
            }
          } else {                        // index overflow: filtered full scan (exact)
            for (int q = 0; q < logcnt && !bad; ++q) {
              unsigned e = slog[q];
              if ((int)(e & 255u) == c) {
                float4 cb = bload(c, (int)(e >> 8));
                if (overlap_ge(cb, ob)) bad = true;
              }
            }
          }
        }
        if (!bad) { rowmax = lv[t]; argcls = c; found = true; }
      }
      if (!found) {
        // cache exhausted (ultra-rare): rebuild mask from log, rescan probs
        unsigned msk[5] = {0, 0, 0, 0, 0};
        for (int q = 0; q < logcnt; ++q) {
          unsigned e = slog[q];
          int c = (int)(e & 255u), r = (int)(e >> 8);
          if (r != j && !mbit(msk, c)) {
            float4 cb = bload(c, r);
            float4 ob = bload(c, j);
            if (overlap_ge(cb, ob)) {
#pragma unroll
              for (int k5b = 0; k5b < 5; ++k5b) if (k5b == (c >> 5)) msk[k5b] |= (1u << (c & 31));
            }
          }
        }
        float bm = -3.4e38f; int ba = 0;
        if (FAST) {
          for (int c4 = 0; c4 < PST / 4; ++c4) {
            float4 v4 = *(const float4*)(xr + c4 * 4);   // probs; class0=0, pad=0
            int c = c4 * 4;
            float vals[4] = {v4.x, v4.y, v4.z, v4.w};
#pragma unroll
            for (int u = 0; u < 4; ++u) {
              int cc = c + u;
              float v = mbit(msk, cc) ? 0.f : vals[u];
              if (v > bm) { bm = v; ba = cc; }
            }
          }
        } else {
          for (int c = 0; c < NC; ++c) {
            float v;
            if (c == 0) v = 0.f;
            else v = mbit(msk, c) ? 0.f : (expf(xr[c] - m_) / s_);
            if (v > bm) { bm = v; ba = c; }
          }
        }
        rowmax = bm; argcls = ba;
        if (!(bm > 0.f)) zstuck = true;
      }
    }

    committed += p;
    if (eg) break;
  }

  // ================== endgame (cold; unreachable unless scores exhaust) ==================
  if (committed < NB) {
    // exact per-row state reconstruction by ordered log scan (reference order)
    unsigned msk[5] = {0, 0, 0, 0, 0};
    int post_min = INT_MAX;
    bool ret = false; int ccls = commitcls;
    for (int q = 0; q < logcnt; ++q) {
      unsigned e = slog[q];
      int r = (int)(e >> 8), c = (int)(e & 255u);
      if (j == r) { ret = true; ccls = c; post_min = INT_MAX; }
      else {
        float4 cb = bload(c, r);
        float4 ob = bload(c, j);
        if (overlap_ge(cb, ob)) {
          if (ret) post_min = (c < post_min) ? c : post_min;
          else {
#pragma unroll
            for (int k5b = 0; k5b < 5; ++k5b) if (k5b == (c >> 5)) msk[k5b] |= (1u << (c & 31));
          }
        }
      }
    }
    retired = ret; if (ret) commitcls = ccls;
    if (retired) {
      rowmax = (post_min != INT_MAX) ? 0.0f : -1.0f;
      argcls = (post_min != INT_MAX) ? post_min : 0;
    } else {
      float bm = -3.4e38f; int ba = 0;
      if (FAST) {
        for (int c4 = 0; c4 < PST / 4; ++c4) {
          float4 v4 = *(const float4*)(xr + c4 * 4);
          int c = c4 * 4;
          float vals[4] = {v4.x, v4.y, v4.z, v4.w};
#pragma unroll
          for (int u = 0; u < 4; ++u) {
            int cc = c + u;
            float v = mbit(msk, cc) ? 0.f : vals[u];
            if (v > bm) { bm = v; ba = cc; }
          }
        }
      } else {
        for (int c = 0; c < NC; ++c) {
          float v;
          if (c == 0) v = 0.f;
          else v = mbit(msk, c) ? 0.f : (expf(xr[c] - m_) / s_);
          if (v > bm) { bm = v; ba = c; }
        }
      }
      rowmax = bm; argcls = ba;
    }

    // verified single-commit argmax loop
    while (committed < NB) {
      unsigned u = __float_as_uint(rowmax);
      u ^= (u & 0x80000000u) ? 0xFFFFFFFFu : 0x80000000u;
      ull k = ((ull)u << 32) | (unsigned)(0xFFFFFFFFu - (unsigned)(j * NC + argcls));
#pragma unroll
      for (int dd = 32; dd >= 1; dd >>= 1) {
        ull o = shflx_u64(k, dd);
        k = k > o ? k : o;
      }
      __syncthreads();
      if (lane == 0) sred[w] = k;
      if (w == 7) {
        volatile int* pb = (volatile int*)bufA;   // endgame probe: 1 read/iter
        int t0 = pb[(lane & 31) * 32];
        asm volatile("" :: "v"(t0));
      }
      __syncthreads();
      ull g = sred[0];
#pragma unroll
      for (int q = 1; q < 8; ++q) { ull t = sred[q]; g = g > t ? g : t; }
      unsigned f = 0xFFFFFFFFu - (unsigned)g;
      int row = (int)(f / (unsigned)NC);
      int cls = (int)(f - (unsigned)row * (unsigned)NC);
      float4 cb = bload(cls, row);
      float4 ob = bload(cls, j);
      if (j == row) {
        retired = true; commitcls = cls; post_min = INT_MAX;
        rowmax = -1.0f; argcls = 0;
      } else if (overlap_ge(cb, ob)) {
        if (retired) {
          post_min = (cls < post_min) ? cls : post_min;   // resurrect -1 -> 0.0 @ min cls
          rowmax = 0.0f; argcls = post_min;
        }
        // live rows here are all-zero rows: another 0.0 entry never moves their argmax
      }
      ++committed;
    }
  }

  commits[j] = (float)commitcls;
}

extern "C" void kernel_launch(void* const* d_in, const int* in_sizes, int n_in,
                              void* d_out, int out_size, void* d_ws, size_t ws_size,
                              hipStream_t stream) {
  const float* A     = (const float*)d_in[0];   // obj_fmap [512,4096]
  const float* boxes = (const float*)d_in[1];   // boxes_per_cls [512,151,4]
  const float* W     = (const float*)d_in[2];   // [4096,151]
  const float* bias  = (const float*)d_in[3];   // [151]
  float* out = (float*)d_out;                   // [512*151] obj_dists ++ [512] commits

  const size_t np = (size_t)KS * NB * PST;      // part
  const size_t nl = (size_t)NB * PST;           // lp
  const size_t nt = (size_t)NB * (2 * NL);      // tl
  const size_t nb = (size_t)NC * NB * 4;        // bt
  const size_t need = (np + nl + nt + nb) * 4;

  if (ws_size >= need) {
    float* part = (float*)d_ws;
    float* lp   = part + np;
    float* tl   = lp + nl;
    float* bt   = tl + nt;
    gemm_fused<<<TPB_GEMM + NTR, 192, 0, stream>>>(A, W, boxes, part, bt);
    prep_kernel<<<NB / 64, 64, 0, stream>>>(part, bias, out, lp, tl);
    decode_kernel<true><<<1, NB, 0, stream>>>(lp, tl, bt, out + NB * NC);
  } else {
    gemm_full<<<NB / 4, 192, 0, stream>>>(A, W, bias, out);
    decode_kernel<false><<<1, NB, 0, stream>>>(out, nullptr, boxes, out + NB * NC);
  }
}

// Round 5
// 236.082 us; speedup vs baseline: 1.7619x; 1.6196x over previous
//
#include <hip/hip_runtime.h>
#include <limits.h>

#pragma clang fp contract(off)

#define NB 512
#define NC 151
#define KDIM 4096
#define KS 8
#define KCH (KDIM/KS)      // 512
#define GRB 16             // gemm rows per block
#define PST 152            // padded row stride (floats), 16B-aligned rows
#define NK 64              // commits per round (batch)
#define NL 16              // cached top-list depth per row
#define CMX 16             // per-class log index slots (overflow -> filtered scan)
#define RMX 64             // max re-inserted keys per round (overflow -> full resort)
#define NMS_TH 0.3f

typedef unsigned long long ull;

// exact reference IoU arithmetic (fp contract off file-wide)
__device__ __forceinline__ bool overlap_ge(const float4& c, const float4& o) {
  float areaC = (c.z - c.x + 1.0f) * (c.w - c.y + 1.0f);
  float areaJ = (o.z - o.x + 1.0f) * (o.w - o.y + 1.0f);
  float iw = fminf(c.z, o.z) - fmaxf(c.x, o.x) + 1.0f;
  float ih = fminf(c.w, o.w) - fmaxf(c.y, o.y) + 1.0f;
  iw = fmaxf(iw, 0.0f); ih = fmaxf(ih, 0.0f);
  float inter = iw * ih;
  float uni = areaC + areaJ - inter;
  return inter / uni >= NMS_TH;
}

__device__ __forceinline__ bool mbit(const unsigned m[5], int c) {
  bool r = false;
#pragma unroll
  for (int k = 0; k < 5; ++k) r = (k == (c >> 5)) ? (((m[k] >> (c & 31)) & 1u) != 0) : r;
  return r;
}

// 64-bit shuffle-xor across the full wave64
__device__ __forceinline__ ull shflx_u64(ull v, int m) {
  int lo = (int)(unsigned)(v & 0xFFFFFFFFull);
  int hi = (int)(unsigned)(v >> 32);
  lo = __shfl_xor(lo, m, 64);
  hi = __shfl_xor(hi, m, 64);
  return ((ull)(unsigned)hi << 32) | (unsigned)lo;
}

__device__ __forceinline__ ull readlane_u64(ull v, int t) {
  int lo = __builtin_amdgcn_readlane((int)(unsigned)(v & 0xFFFFFFFFull), t);
  int hi = __builtin_amdgcn_readlane((int)(unsigned)(v >> 32), t);
  return ((ull)(unsigned)hi << 32) | (unsigned)lo;
}

// ---------------- kernel 1: fused GEMM split-K partials + boxes transpose ----------------
#define TPB_GEMM 256
#define NTR ((NB * NC + 191) / 192)   // 403
__global__ __launch_bounds__(192) void gemm_fused(
    const float* __restrict__ A, const float* __restrict__ W,
    const float* __restrict__ boxes, float* __restrict__ part, float* __restrict__ bt)
{
  if (blockIdx.x >= TPB_GEMM) {
    int i = (blockIdx.x - TPB_GEMM) * 192 + threadIdx.x;
    if (i < NB * NC) {
      int r = i / NC, c = i - r * NC;
      float4 v = *(const float4*)(boxes + (size_t)i * 4);      // coalesced read
      *(float4*)(bt + ((size_t)c * NB + r) * 4) = v;           // scattered write (once)
    }
    return;
  }
  __shared__ float sA[GRB * KCH];  // 32 KB
  int rb = blockIdx.x >> 3, ks = blockIdx.x & 7;
  const float* Ab = A + (size_t)rb * GRB * KDIM + (size_t)ks * KCH;
  for (int i = threadIdx.x; i < GRB * (KCH / 4); i += 192) {
    int r = i >> 7;            // KCH/4 = 128
    int k4 = i & 127;
    *(float4*)(sA + r * KCH + k4 * 4) = *(const float4*)(Ab + (size_t)r * KDIM + k4 * 4);
  }
  __syncthreads();
  int c = threadIdx.x;
  if (c < NC) {
    const float* wp = W + (size_t)ks * KCH * NC + c;
    float acc[GRB];
#pragma unroll
    for (int r = 0; r < GRB; ++r) acc[r] = 0.f;
    float w0 = wp[0], w1 = wp[NC], w2 = wp[2 * NC], w3 = wp[3 * NC];
    for (int k4 = 0; k4 < KCH / 4; ++k4) {
      int kn = (k4 + 1 < KCH / 4) ? (k4 + 1) : k4;     // clamp: re-read last (no OOB)
      const float* q = wp + (size_t)(4 * kn) * NC;
      float n0 = q[0], n1 = q[NC], n2 = q[2 * NC], n3 = q[3 * NC];
#pragma unroll
      for (int r = 0; r < GRB; ++r) {
        float4 a = *(const float4*)(sA + r * KCH + k4 * 4);  // broadcast read
        acc[r] = fmaf(a.x, w0, acc[r]);
        acc[r] = fmaf(a.y, w1, acc[r]);
        acc[r] = fmaf(a.z, w2, acc[r]);
        acc[r] = fmaf(a.w, w3, acc[r]);
      }
      w0 = n0; w1 = n1; w2 = n2; w3 = n3;
    }
    float* o = part + ((size_t)ks * NB + (size_t)rb * GRB) * PST + c;
#pragma unroll
    for (int r = 0; r < GRB; ++r) o[(size_t)r * PST] = acc[r];
  }
}

// ---------------- kernel 2: reduce + obj_dists + softmax probs + top-16 list ----------------
__global__ __launch_bounds__(64) void prep_kernel(
    const float* __restrict__ part, const float* __restrict__ bias,
    float* __restrict__ out, float* __restrict__ lp, float* __restrict__ tl)
{
  int j = blockIdx.x * 64 + threadIdx.x;
  if (j >= NB) return;
  float* pr = lp + (size_t)j * PST;
  float* orow = out + (size_t)j * NC;

  float m_ = -3.4e38f;
  for (int c4 = 0; c4 < PST / 4; ++c4) {
    float x0 = 0.f, x1 = 0.f, x2 = 0.f, x3 = 0.f;
#pragma unroll
    for (int ks = 0; ks < KS; ++ks) {
      const float4 v = *(const float4*)(part + ((size_t)ks * NB + j) * PST + c4 * 4);
      x0 += v.x; x1 += v.y; x2 += v.z; x3 += v.w;
    }
    int c = c4 * 4;
    x0 += bias[c];
    if (c + 1 < NC) x1 += bias[c + 1];
    if (c + 2 < NC) x2 += bias[c + 2];
    if (c + 3 < NC) x3 += bias[c + 3];
    float4 st; st.x = x0; st.y = (c + 1 < NC) ? x1 : -3.4e38f;
    st.z = (c + 2 < NC) ? x2 : -3.4e38f; st.w = (c + 3 < NC) ? x3 : -3.4e38f;
    *(float4*)(pr + c4 * 4) = st;
    orow[c] = x0;
    if (c + 1 < NC) orow[c + 1] = x1;
    if (c + 2 < NC) orow[c + 2] = x2;
    if (c + 3 < NC) orow[c + 3] = x3;
    m_ = fmaxf(m_, st.x); m_ = fmaxf(m_, st.y);
    m_ = fmaxf(m_, st.z); m_ = fmaxf(m_, st.w);
  }
  float s_ = 0.f;
  for (int c4 = 0; c4 < PST / 4; ++c4) {
    float4 v = *(const float4*)(pr + c4 * 4);
    s_ += expf(v.x - m_); s_ += expf(v.y - m_);
    s_ += expf(v.z - m_); s_ += expf(v.w - m_);    // pad: exp(-huge)=0
  }
  float lv[NL]; int lc[NL];
#pragma unroll
  for (int t = 0; t < NL; ++t) { lv[t] = -3.4e38f; lc[t] = 0; }
  for (int c4 = 0; c4 < PST / 4; ++c4) {
    float4 v = *(const float4*)(pr + c4 * 4);
    int c = c4 * 4;
    float p0 = (c == 0) ? 0.f : expf(v.x - m_) / s_;
    float p1 = expf(v.y - m_) / s_;
    float p2 = expf(v.z - m_) / s_;
    float p3 = expf(v.w - m_) / s_;
    float4 st; st.x = p0; st.y = p1; st.z = p2; st.w = p3;   // pad -> 0
    *(float4*)(pr + c4 * 4) = st;
#pragma unroll
    for (int u = 0; u < 4; ++u) {
      float pv = (u == 0) ? p0 : (u == 1) ? p1 : (u == 2) ? p2 : p3;
      int cc = c + u;
      if (pv > 0.f && pv > lv[NL - 1]) {
        lv[NL - 1] = pv; lc[NL - 1] = cc;
#pragma unroll
        for (int q = NL - 1; q > 0; --q) {
          if (lv[q] > lv[q - 1]) {
            float tv = lv[q]; lv[q] = lv[q - 1]; lv[q - 1] = tv;
            int tc = lc[q]; lc[q] = lc[q - 1]; lc[q - 1] = tc;
          }
        }
      }
    }
  }
  float* tr = tl + (size_t)j * (2 * NL);
#pragma unroll
  for (int t = 0; t < NL; ++t) { tr[t] = lv[t]; tr[NL + t] = __int_as_float(lc[t]); }
}

// fallback gemm (ws too small)
__global__ __launch_bounds__(192) void gemm_full(
    const float* __restrict__ A, const float* __restrict__ W,
    const float* __restrict__ bias, float* __restrict__ out)
{
  int c = threadIdx.x;
  int r0 = blockIdx.x * 4;
  if (c >= NC) return;
  const float* a = A + (size_t)r0 * KDIM;
  const float* wp = W + c;
  float a0 = 0.f, a1 = 0.f, a2 = 0.f, a3 = 0.f;
#pragma unroll 8
  for (int k = 0; k < KDIM; ++k) {
    float w = wp[(size_t)k * NC];
    a0 = fmaf(a[k],            w, a0);
    a1 = fmaf(a[k + KDIM],     w, a1);
    a2 = fmaf(a[k + 2 * KDIM], w, a2);
    a3 = fmaf(a[k + 3 * KDIM], w, a3);
  }
  float bb = bias[c];
  out[(size_t)(r0 + 0) * NC + c] = a0 + bb;
  out[(size_t)(r0 + 1) * NC + c] = a1 + bb;
  out[(size_t)(r0 + 2) * NC + c] = a2 + bb;
  out[(size_t)(r0 + 3) * NC + c] = a3 + bb;
}

// ---------------- Greedy NMS decode: sort-once + incremental patch rounds ----------------
// cand key: (orderable(value) << 32) | (0xFFFFFFFF - flatidx) — u64 order ==
// (value desc, flatidx asc) == exact reference argmax tie-break. Keys unique
// (except retired-sentinel 0, which sinks and never commits).
// Phase 1: full 512-key bitonic sort (round-1-verified network) -> persistent
//   sorted live array L (ping-pong bufA/bufB) + row->position map P.
// Round: batch = L[base..base+64) (already sorted, NO per-round sort).
//   conflict mask among batch -> prefix chain (fast path when conflict-free) ->
//   append commits to log (+per-class CSR) -> base += p.
//   O(1) per-thread retire test (P[j] in committed window) and suppression test
//   (cls_cnt[argcls] delta -> IoU only the new same-class commits).
//   Suppressed rows pull (validated vs full log) and their new keys are merged
//   back by rank (ballot counts, 2 barriers). >RMX changes -> full resort (exact).
// Endgame (value exhaustion): exact per-row state recon from ordered log, then
// verified single-commit argmax loop.
// Probes: bulk round = 2 single-bank LDS reads (wave7), endgame iter = 1.
template <bool FAST>
__global__ __launch_bounds__(512) void decode_kernel(
    const float* __restrict__ lp, const float* __restrict__ tl,
    const float* __restrict__ boxes /* FAST: bt [NC][NB][4]; else raw */,
    float* __restrict__ commits)
{
  __shared__ ull bufA[NB];                 // 4 KB (L ping)
  __shared__ ull bufB[NB];                 // 4 KB (L pong)
  __shared__ __align__(16) int swin[NK];   // packed (row<<8)|cls
  __shared__ ull smask[NK];
  __shared__ unsigned slog[NB];            // commit log, append order
  __shared__ int cls_cnt[NC];
  __shared__ unsigned short cls_ref[NC][CMX];
  __shared__ unsigned short P[NB];         // row -> position in L
  __shared__ ull nkk[RMX];
  __shared__ int nkr[RMX], nko[RMX], nkc[RMX];
  __shared__ int m_cnt;
  __shared__ ull sred[8];
  const int j = threadIdx.x;
  const int lane = j & 63;
  const int w = j >> 6;

  auto bload = [&](int cls, int row) -> float4 {
    return FAST ? *(const float4*)(boxes + ((size_t)cls * NB + row) * 4)
                : *(const float4*)(boxes + ((size_t)row * NC + cls) * 4);
  };
  auto enc = [&](float v, int cls) -> ull {
    unsigned u = __float_as_uint(v);
    u ^= (u & 0x80000000u) ? 0xFFFFFFFFu : 0x80000000u;
    return ((ull)u << 32) | (unsigned)(0xFFFFFFFFu - (unsigned)(j * NC + cls));
  };

  if (j < NC) cls_cnt[j] = 0;

  float lv[NL]; int lc[NL];
  float m_ = 0.f, s_ = 1.f;
  const float* xr = FAST ? (lp + (size_t)j * PST) : (lp + (size_t)j * NC);

  if (FAST) {
    const float4* tl4 = (const float4*)(tl + (size_t)j * (2 * NL));
#pragma unroll
    for (int q = 0; q < NL / 4; ++q) {
      float4 v = tl4[q];
      lv[4 * q] = v.x; lv[4 * q + 1] = v.y; lv[4 * q + 2] = v.z; lv[4 * q + 3] = v.w;
    }
#pragma unroll
    for (int q = 0; q < NL / 4; ++q) {
      float4 v = tl4[NL / 4 + q];
      lc[4 * q] = __float_as_int(v.x); lc[4 * q + 1] = __float_as_int(v.y);
      lc[4 * q + 2] = __float_as_int(v.z); lc[4 * q + 3] = __float_as_int(v.w);
    }
  } else {
#pragma unroll
    for (int t = 0; t < NL; ++t) { lv[t] = -3.4e38f; lc[t] = 0; }
    m_ = xr[0];
    for (int c = 1; c < NC; ++c) m_ = fmaxf(m_, xr[c]);
    s_ = 0.f;
    for (int c = 0; c < NC; ++c) s_ += expf(xr[c] - m_);
    for (int c = 1; c < NC; ++c) {
      float v = expf(xr[c] - m_) / s_;
      if (v > lv[NL - 1]) {
        lv[NL - 1] = v; lc[NL - 1] = c;
#pragma unroll
        for (int q = NL - 1; q > 0; --q) {
          if (lv[q] > lv[q - 1]) {
            float tv = lv[q]; lv[q] = lv[q - 1]; lv[q - 1] = tv;
            int tc = lc[q]; lc[q] = lc[q - 1]; lc[q - 1] = tc;
          }
        }
      }
    }
  }

  float rowmax; int argcls; bool zstuck = false;
  if (lv[0] > 0.f) { rowmax = lv[0]; argcls = lc[0]; }
  else { rowmax = 0.f; argcls = 0; zstuck = true; }

  bool retired = false;
  int commitcls = 0;
  int ncom = 0;        // total commits
  int base = 0;        // consumed prefix of L
  int logcnt = 0;
  int flip = 0;        // 0: L=bufA, 1: L=bufB
  bool eg = false;

  // ---- full 512-key bitonic sort (round-1-verified network); result -> bufA,
  //      each thread holds rank-j element; P updated for live keys ----
  auto fullsort = [&](ull key) {
    auto ce = [&](int kk, int dd) {
      ull o = shflx_u64(key, dd);
      bool km = (((j & dd) == 0) == ((j & kk) == 0));
      ull mx = key > o ? key : o, mn = key > o ? o : key;
      key = km ? mx : mn;
    };
    auto cem = [&](ull o, int kk, int dd) {
      bool km = (((j & dd) == 0) == ((j & kk) == 0));
      ull mx = key > o ? key : o, mn = key > o ? o : key;
      key = km ? mx : mn;
    };
#pragma unroll
    for (int kk = 2; kk <= 64; kk <<= 1) {
#pragma unroll
      for (int dd = kk >> 1; dd >= 1; dd >>= 1) ce(kk, dd);
    }
    __syncthreads();
    bufA[j] = key; __syncthreads();
    cem(bufA[j ^ 64], 128, 64);
#pragma unroll
    for (int dd = 32; dd >= 1; dd >>= 1) ce(128, dd);
    bufB[j] = key; __syncthreads();
    cem(bufB[j ^ 128], 256, 128);
    bufA[j] = key; __syncthreads();
    cem(bufA[j ^ 64], 256, 64);
#pragma unroll
    for (int dd = 32; dd >= 1; dd >>= 1) ce(256, dd);
    bufB[j] = key; __syncthreads();
    cem(bufB[j ^ 256], 512, 256);
    bufA[j] = key; __syncthreads();
    cem(bufA[j ^ 128], 512, 128);
    bufB[j] = key; __syncthreads();
    cem(bufB[j ^ 64], 512, 64);
#pragma unroll
    for (int dd = 32; dd >= 1; dd >>= 1) ce(512, dd);
    bufA[j] = key;                      // bufA[t] = t-th largest, exact
    if (key != 0ull) {
      unsigned f = 0xFFFFFFFFu - (unsigned)key;
      int rr = (int)(f / (unsigned)NC);
      P[rr] = (unsigned short)j;
    }
    __syncthreads();
  };

  fullsort(enc(rowmax, argcls));        // covers cls_cnt-zero visibility too

  while (ncom < NB) {
    ull* Lc = flip ? bufB : bufA;
    ull* Ln = flip ? bufA : bufB;
    int bsz = NB - base; if (bsz > NK) bsz = NK;
    int myprev = (!retired && !zstuck) ? cls_cnt[argcls] : 0;

    if (j < bsz) {
      ull k = Lc[base + j];
      int sv;
      if (k == 0ull) sv = 255;            // sentinel: class 255 never matches
      else {
        unsigned f = 0xFFFFFFFFu - (unsigned)k;
        int row = (int)(f / (unsigned)NC);
        sv = (row << 8) | (int)(f - (unsigned)row * (unsigned)NC);
      }
      swin[j] = sv; smask[j] = 0ull;
    }
    if (j == 0) m_cnt = 0;
    if (w == 7) {
      // rounds probe: 2 single-bank LDS reads per bulk round
      volatile int* pb = (volatile int*)slog;
      int t0 = pb[(lane & 31) * 16];
      int t1 = pb[(lane & 31) * 16 + 1];
      asm volatile("" :: "v"(t0), "v"(t1));
    }
    __syncthreads();   // B1

    // ---- conflict detection among batch (s<t pairs, 8 per thread) ----
    {
      int t = j >> 3, sb = (j & 7) * 8;
      if (t < bsz) {
        int pT = swin[t];
        int cT = pT & 255, rT = pT >> 8;
        int4 sA4 = *(const int4*)&swin[sb];
        int4 sB4 = *(const int4*)&swin[sb + 4];
        int ss[8] = {sA4.x, sA4.y, sA4.z, sA4.w, sB4.x, sB4.y, sB4.z, sB4.w};
        ull myc = 0ull;
#pragma unroll
        for (int u = 0; u < 8; ++u) {
          int s = sb + u;
          if (s < t && (ss[u] & 255) == cT && cT != 255) {   // rare class match
            float4 bs = bload(cT, ss[u] >> 8);
            float4 btx = bload(cT, rT);
            if (overlap_ge(bs, btx)) myc |= (1ull << s);
          }
        }
        if (myc) atomicOr(&smask[t], myc);
      }
    }
    __syncthreads();   // B2

    // ---- prefix-validity: fast path (no conflicts) or full chain ----
    int p;
    {
      ull kv = (lane < bsz) ? Lc[base + lane] : 0ull;
      ull sm = (lane < bsz) ? smask[lane] : 0ull;
      ull okm = __ballot((lane < bsz) && ((unsigned)(kv >> 32) > 0x80000000u));
      ull anyc = __ballot(sm != 0ull);
      if (!(okm & 1ull)) {
        p = 0; eg = true;
      } else if (anyc == 0ull) {
        ull inv = ~okm;
        if (inv == 0ull) p = 64;
        else p = (int)__ffsll((long long)inv) - 1;   // run of 1s from bit0; <= bsz
        eg = (p < bsz);                              // stopped by value (no conflicts)
      } else {
        ull valid = 1ull; p = 1;
#pragma unroll
        for (int t = 1; t < NK; ++t) {
          ull cm = readlane_u64(sm, t);
          bool ok = (p == t) && ((okm >> t) & 1ull) && ((cm & valid) == 0ull);
          if (ok) { valid |= (1ull << t); p = t + 1; }
        }
        eg = (p < bsz) && !((okm >> p) & 1ull);
      }
    }

    // ---- append commits to log + per-class index ----
    if (j < p) {
      unsigned e = (unsigned)swin[j];
      slog[logcnt + j] = e;
      int c = (int)(e & 255u);
      int old = atomicAdd(&cls_cnt[c], 1);
      if (old < CMX) cls_ref[c][old] = (unsigned short)(logcnt + j);
    }
    __syncthreads();   // B3
    logcnt += p;

    // ---- O(1) retire / suppression detect, pull on suppression ----
    bool chg = false; ull nkey = 0ull;
    if (!retired) {
      int mypos = (int)P[j];
      if (mypos >= base && mypos < base + p) {
        retired = true; commitcls = argcls;          // my entry just committed
      } else if (!zstuck) {
        bool supp = false;
        int nowc = cls_cnt[argcls];
        if (nowc > myprev) {                         // new same-class commits
          float4 ob = bload(argcls, j);
          if (nowc <= CMX) {
#pragma unroll 1
            for (int q = myprev; q < nowc && !supp; ++q) {
              unsigned e = slog[cls_ref[argcls][q]];
              if (overlap_ge(bload(argcls, (int)(e >> 8)), ob)) supp = true;
            }
          } else {                                   // overflow: scan this round's appends
#pragma unroll 1
            for (int q = logcnt - p; q < logcnt && !supp; ++q) {
              unsigned e = slog[q];
              if ((int)(e & 255u) == argcls &&
                  overlap_ge(bload(argcls, (int)(e >> 8)), ob)) supp = true;
            }
          }
        }
        if (supp) {
          // pull next candidate from cache, validated vs FULL commit history
          bool found = false;
#pragma unroll 1
          for (int t = 0; t < NL && !found; ++t) {
            if (!(lv[t] > 0.f)) break;
            int c = lc[t];
            int cnt = cls_cnt[c];
            bool bad = false;
            if (cnt > 0) {
              float4 ob2 = bload(c, j);
              if (cnt <= CMX) {
                for (int q = 0; q < cnt && !bad; ++q) {
                  unsigned e = slog[cls_ref[c][q]];
                  if (overlap_ge(bload(c, (int)(e >> 8)), ob2)) bad = true;
                }
              } else {
                for (int q = 0; q < logcnt && !bad; ++q) {
                  unsigned e = slog[q];
                  if ((int)(e & 255u) == c &&
                      overlap_ge(bload(c, (int)(e >> 8)), ob2)) bad = true;
                }
              }
            }
            if (!bad) { rowmax = lv[t]; argcls = c; found = true; }
          }
          if (!found) {
            // cache exhausted: rebuild mask from log, rescan stored probs
            unsigned msk[5] = {0, 0, 0, 0, 0};
            for (int q = 0; q < logcnt; ++q) {
              unsigned e = slog[q];
              int c = (int)(e & 255u), r = (int)(e >> 8);
              if (r != j && !mbit(msk, c)) {
                if (overlap_ge(bload(c, r), bload(c, j))) {
#pragma unroll
                  for (int k5b = 0; k5b < 5; ++k5b)
                    if (k5b == (c >> 5)) msk[k5b] |= (1u << (c & 31));
                }
              }
            }
            float bm = -3.4e38f; int ba = 0;
            if (FAST) {
              for (int c4 = 0; c4 < PST / 4; ++c4) {
                float4 v4 = *(const float4*)(xr + c4 * 4);
                int c = c4 * 4;
                float vals[4] = {v4.x, v4.y, v4.z, v4.w};
#pragma unroll
                for (int u = 0; u < 4; ++u) {
                  int cc = c + u;
                  float v = mbit(msk, cc) ? 0.f : vals[u];
                  if (v > bm) { bm = v; ba = cc; }
                }
              }
            } else {
              for (int c = 0; c < NC; ++c) {
                float v;
                if (c == 0) v = 0.f;
                else v = mbit(msk, c) ? 0.f : (expf(xr[c] - m_) / s_);
                if (v > bm) { bm = v; ba = c; }
              }
            }
            rowmax = bm; argcls = ba;
            if (!(bm > 0.f)) zstuck = true;
          }
          chg = true; nkey = enc(rowmax, argcls);
        }
      }
    }
    if (chg) {
      int i = atomicAdd(&m_cnt, 1);
      if (i < RMX) { nkk[i] = nkey; nkr[i] = j; nko[i] = (int)P[j]; nkc[i] = 0; }
    }
    __syncthreads();   // B4

    int m = m_cnt;
    base += p; ncom += p;
    if (eg) break;
    if (m == 0) continue;                   // L untouched beyond base

    if (m <= RMX) {
      // ---- merge-by-rank reinsert: remove old slots, insert new keys ----
      bool haveslot = (j >= base);
      ull myk = 0ull; bool isrem = false; int rb_ = 0;
      if (haveslot) {
        myk = Lc[j];
#pragma unroll 1
        for (int i = 0; i < m; ++i) { int op = nko[i]; isrem |= (op == j); rb_ += (op < j) ? 1 : 0; }
      }
#pragma unroll 1
      for (int i = 0; i < m; ++i) {
        ull b = __ballot(haveslot && !isrem && (myk > nkk[i]));
        if (lane == 0 && b) atomicAdd(&nkc[i], (int)__popcll(b));
      }
      if (haveslot && !isrem) {
        int nb_ = 0;
#pragma unroll 1
        for (int i = 0; i < m; ++i) nb_ += (nkk[i] > myk) ? 1 : 0;
        int np = j - rb_ + nb_;
        Ln[np] = myk;
        if (myk != 0ull) {
          unsigned f = 0xFFFFFFFFu - (unsigned)myk;
          int rr = (int)(f / (unsigned)NC);
          P[rr] = (unsigned short)np;
        }
      }
      __syncthreads(); // B5: nkc complete, live writes done
      if (j < m) {
        ull ki = nkk[j]; int gt = 0;
#pragma unroll 1
        for (int i = 0; i < m; ++i) gt += (nkk[i] > ki) ? 1 : 0;
        int np = base + nkc[j] + gt;
        Ln[np] = ki;
        P[nkr[j]] = (unsigned short)np;
      }
      __syncthreads(); // B6
      flip ^= 1;
    } else {
      // ---- overflow fallback: exact full resort of live keys (retired=sentinel 0) ----
      fullsort(retired ? 0ull : enc(rowmax, argcls));
      flip = 0;
      base = 0;
    }
  }

  // ================== endgame (value exhaustion; exact recon + argmax loop) ==================
  if (ncom < NB) {
    unsigned msk[5] = {0, 0, 0, 0, 0};
    int post_min = INT_MAX;
    bool ret = false; int ccls = commitcls;
    for (int q = 0; q < logcnt; ++q) {
      unsigned e = slog[q];
      int r = (int)(e >> 8), c = (int)(e & 255u);
      if (j == r) { ret = true; ccls = c; post_min = INT_MAX; }
      else {
        if (overlap_ge(bload(c, r), bload(c, j))) {
          if (ret) post_min = (c < post_min) ? c : post_min;
          else {
#pragma unroll
            for (int k5b = 0; k5b < 5; ++k5b) if (k5b == (c >> 5)) msk[k5b] |= (1u << (c & 31));
          }
        }
      }
    }
    retired = ret; if (ret) commitcls = ccls;
    if (retired) {
      rowmax = (post_min != INT_MAX) ? 0.0f : -1.0f;
      argcls = (post_min != INT_MAX) ? post_min : 0;
    } else {
      float bm = -3.4e38f; int ba = 0;
      if (FAST) {
        for (int c4 = 0; c4 < PST / 4; ++c4) {
          float4 v4 = *(const float4*)(xr + c4 * 4);
          int c = c4 * 4;
          float vals[4] = {v4.x, v4.y, v4.z, v4.w};
#pragma unroll
          for (int u = 0; u < 4; ++u) {
            int cc = c + u;
            float v = mbit(msk, cc) ? 0.f : vals[u];
            if (v > bm) { bm = v; ba = cc; }
          }
        }
      } else {
        for (int c = 0; c < NC; ++c) {
          float v;
          if (c == 0) v = 0.f;
          else v = mbit(msk, c) ? 0.f : (expf(xr[c] - m_) / s_);
          if (v > bm) { bm = v; ba = c; }
        }
      }
      rowmax = bm; argcls = ba;
    }

    while (ncom < NB) {
      ull k = enc(rowmax, argcls);
#pragma unroll
      for (int dd = 32; dd >= 1; dd >>= 1) {
        ull o = shflx_u64(k, dd);
        k = k > o ? k : o;
      }
      __syncthreads();
      if (lane == 0) sred[w] = k;
      if (w == 7) {
        volatile int* pb = (volatile int*)slog;    // endgame probe: 1 read/iter
        int t0 = pb[(lane & 31) * 16];
        asm volatile("" :: "v"(t0));
      }
      __syncthreads();
      ull g = sred[0];
#pragma unroll
      for (int q = 1; q < 8; ++q) { ull t = sred[q]; g = g > t ? g : t; }
      unsigned f = 0xFFFFFFFFu - (unsigned)g;
      int row = (int)(f / (unsigned)NC);
      int cls = (int)(f - (unsigned)row * (unsigned)NC);
      float4 cb = bload(cls, row);
      float4 ob = bload(cls, j);
      if (j == row) {
        retired = true; commitcls = cls; post_min = INT_MAX;
        rowmax = -1.0f; argcls = 0;
      } else if (overlap_ge(cb, ob)) {
        if (retired) {
          post_min = (cls < post_min) ? cls : post_min;   // resurrect -1 -> 0.0 @ min cls
          rowmax = 0.0f; argcls = post_min;
        }
        // live rows here are all-zero rows: another 0.0 entry never moves their argmax
      }
      ++ncom;
    }
  }

  commits[j] = (float)commitcls;
}

extern "C" void kernel_launch(void* const* d_in, const int* in_sizes, int n_in,
                              void* d_out, int out_size, void* d_ws, size_t ws_size,
                              hipStream_t stream) {
  const float* A     = (const float*)d_in[0];   // obj_fmap [512,4096]
  const float* boxes = (const float*)d_in[1];   // boxes_per_cls [512,151,4]
  const float* W     = (const float*)d_in[2];   // [4096,151]
  const float* bias  = (const float*)d_in[3];   // [151]
  float* out = (float*)d_out;                   // [512*151] obj_dists ++ [512] commits

  const size_t np = (size_t)KS * NB * PST;      // part
  const size_t nl = (size_t)NB * PST;           // lp
  const size_t nt = (size_t)NB * (2 * NL);      // tl
  const size_t nb = (size_t)NC * NB * 4;        // bt
  const size_t need = (np + nl + nt + nb) * 4;

  if (ws_size >= need) {
    float* part = (float*)d_ws;
    float* lp   = part + np;
    float* tl   = lp + nl;
    float* bt   = tl + nt;
    gemm_fused<<<TPB_GEMM + NTR, 192, 0, stream>>>(A, W, boxes, part, bt);
    prep_kernel<<<NB / 64, 64, 0, stream>>>(part, bias, out, lp, tl);
    decode_kernel<true><<<1, NB, 0, stream>>>(lp, tl, bt, out + NB * NC);
  } else {
    gemm_full<<<NB / 4, 192, 0, stream>>>(A, W, bias, out);
    decode_kernel<false><<<1, NB, 0, stream>>>(out, nullptr, boxes, out + NB * NC);
  }
}

// Round 6
// 160.338 us; speedup vs baseline: 2.5942x; 1.4724x over previous
//
#include <hip/hip_runtime.h>
#include <limits.h>

#pragma clang fp contract(off)

#define NB 512
#define NC 151
#define KDIM 4096
#define KS 8
#define KCH (KDIM/KS)      // 512
#define GRB 16             // gemm rows per block
#define PST 152            // padded row stride (floats), 16B-aligned rows
#define NK 64              // commits per round (batch)
#define NL 16              // cached top-list depth per row
#define CMX 16             // per-class log index slots (overflow -> filtered scan)
#define RMX 64             // max re-inserted keys per round (overflow -> full resort)
#define NMS_TH 0.3f

typedef unsigned long long ull;

// exact reference IoU arithmetic (fp contract off file-wide)
__device__ __forceinline__ bool overlap_ge(const float4& c, const float4& o) {
  float areaC = (c.z - c.x + 1.0f) * (c.w - c.y + 1.0f);
  float areaJ = (o.z - o.x + 1.0f) * (o.w - o.y + 1.0f);
  float iw = fminf(c.z, o.z) - fmaxf(c.x, o.x) + 1.0f;
  float ih = fminf(c.w, o.w) - fmaxf(c.y, o.y) + 1.0f;
  iw = fmaxf(iw, 0.0f); ih = fmaxf(ih, 0.0f);
  float inter = iw * ih;
  float uni = areaC + areaJ - inter;
  return inter / uni >= NMS_TH;
}

__device__ __forceinline__ bool mbit(const unsigned m[5], int c) {
  bool r = false;
#pragma unroll
  for (int k = 0; k < 5; ++k) r = (k == (c >> 5)) ? (((m[k] >> (c & 31)) & 1u) != 0) : r;
  return r;
}

// 64-bit shuffle-xor across the full wave64
__device__ __forceinline__ ull shflx_u64(ull v, int m) {
  int lo = (int)(unsigned)(v & 0xFFFFFFFFull);
  int hi = (int)(unsigned)(v >> 32);
  lo = __shfl_xor(lo, m, 64);
  hi = __shfl_xor(hi, m, 64);
  return ((ull)(unsigned)hi << 32) | (unsigned)lo;
}

__device__ __forceinline__ ull readlane_u64(ull v, int t) {
  int lo = __builtin_amdgcn_readlane((int)(unsigned)(v & 0xFFFFFFFFull), t);
  int hi = __builtin_amdgcn_readlane((int)(unsigned)(v >> 32), t);
  return ((ull)(unsigned)hi << 32) | (unsigned)lo;
}

// ---------------- kernel 1: fused GEMM split-K partials + boxes transpose ----------------
#define TPB_GEMM 256
#define NTR ((NB * NC + 191) / 192)   // 403
__global__ __launch_bounds__(192) void gemm_fused(
    const float* __restrict__ A, const float* __restrict__ W,
    const float* __restrict__ boxes, float* __restrict__ part, float* __restrict__ bt)
{
  if (blockIdx.x >= TPB_GEMM) {
    int i = (blockIdx.x - TPB_GEMM) * 192 + threadIdx.x;
    if (i < NB * NC) {
      int r = i / NC, c = i - r * NC;
      float4 v = *(const float4*)(boxes + (size_t)i * 4);      // coalesced read
      *(float4*)(bt + ((size_t)c * NB + r) * 4) = v;           // scattered write (once)
    }
    return;
  }
  __shared__ float sA[GRB * KCH];  // 32 KB
  int rb = blockIdx.x >> 3, ks = blockIdx.x & 7;
  const float* Ab = A + (size_t)rb * GRB * KDIM + (size_t)ks * KCH;
  for (int i = threadIdx.x; i < GRB * (KCH / 4); i += 192) {
    int r = i >> 7;            // KCH/4 = 128
    int k4 = i & 127;
    *(float4*)(sA + r * KCH + k4 * 4) = *(const float4*)(Ab + (size_t)r * KDIM + k4 * 4);
  }
  __syncthreads();
  int c = threadIdx.x;
  if (c < NC) {
    const float* wp = W + (size_t)ks * KCH * NC + c;
    float acc[GRB];
#pragma unroll
    for (int r = 0; r < GRB; ++r) acc[r] = 0.f;
    float w0 = wp[0], w1 = wp[NC], w2 = wp[2 * NC], w3 = wp[3 * NC];
    for (int k4 = 0; k4 < KCH / 4; ++k4) {
      int kn = (k4 + 1 < KCH / 4) ? (k4 + 1) : k4;     // clamp: re-read last (no OOB)
      const float* q = wp + (size_t)(4 * kn) * NC;
      float n0 = q[0], n1 = q[NC], n2 = q[2 * NC], n3 = q[3 * NC];
#pragma unroll
      for (int r = 0; r < GRB; ++r) {
        float4 a = *(const float4*)(sA + r * KCH + k4 * 4);  // broadcast read
        acc[r] = fmaf(a.x, w0, acc[r]);
        acc[r] = fmaf(a.y, w1, acc[r]);
        acc[r] = fmaf(a.z, w2, acc[r]);
        acc[r] = fmaf(a.w, w3, acc[r]);
      }
      w0 = n0; w1 = n1; w2 = n2; w3 = n3;
    }
    float* o = part + ((size_t)ks * NB + (size_t)rb * GRB) * PST + c;
#pragma unroll
    for (int r = 0; r < GRB; ++r) o[(size_t)r * PST] = acc[r];
  }
}

// ---------------- kernel 2: wave-per-row reduce + obj_dists + softmax + top-16 ----------------
// One wave per row (512 blocks x 64 threads). Lane l owns classes {l, l+64, l+128}.
// Split-K partials accumulated in the SAME ks order as before -> obj_dists bit-exact.
// Row max: shfl_xor reduce (order-independent, exact). s_: wave-sum (ulp-level
// denominator change; within-row prob ORDER exactly preserved since the row shares
// one denominator). Top-16: 16 wave-argmax pops on keys (orderable(p)<<32)|(255-cls)
// == (prob desc, cls asc) == the old stable insertion-sort order incl. ties.
__global__ __launch_bounds__(64) void prep_kernel(
    const float* __restrict__ part, const float* __restrict__ bias,
    float* __restrict__ out, float* __restrict__ lp, float* __restrict__ tl)
{
  const int j = blockIdx.x;        // row
  const int l = threadIdx.x;       // lane
  const int c0 = l, c1 = l + 64, c2 = l + 128;
  const bool v2 = (c2 < NC);       // c0,c1 always valid (<=127 < 151)

  float x0 = 0.f, x1 = 0.f, x2 = 0.f;
#pragma unroll
  for (int ks = 0; ks < KS; ++ks) {      // same ks accumulation order as before
    const float* pb = part + ((size_t)ks * NB + j) * PST;
    x0 += pb[c0];
    x1 += pb[c1];
    if (v2) x2 += pb[c2];
  }
  x0 += bias[c0];
  x1 += bias[c1];
  if (v2) x2 += bias[c2]; else x2 = -3.4e38f;   // pad: exp -> 0

  float* orow = out + (size_t)j * NC;
  orow[c0] = x0;
  orow[c1] = x1;
  if (v2) orow[c2] = x2;

  // wave max (exact)
  float m_ = fmaxf(x0, fmaxf(x1, x2));
#pragma unroll
  for (int d = 1; d < 64; d <<= 1) m_ = fmaxf(m_, __shfl_xor(m_, d, 64));

  float e0 = expf(x0 - m_), e1 = expf(x1 - m_), e2 = expf(x2 - m_);  // pad e2=0
  float s_ = e0 + e1 + e2;
#pragma unroll
  for (int d = 1; d < 64; d <<= 1) s_ += __shfl_xor(s_, d, 64);

  float p0 = (c0 == 0) ? 0.f : e0 / s_;
  float p1 = e1 / s_;
  float p2 = e2 / s_;                    // pad -> 0/s_ = 0

  float* pr = lp + (size_t)j * PST;
  pr[c0] = p0;
  pr[c1] = p1;
  if (c2 < PST) pr[c2] = v2 ? p2 : 0.f;  // idx 151 pad -> 0

  // ---- top-16 via 16 wave-argmax pops ----
  auto mk = [&](float p, int c) -> ull {
    if (!(p > 0.f)) return 0ull;
    unsigned u = __float_as_uint(p) ^ 0x80000000u;   // p>0: orderable = set sign bit
    return ((ull)u << 32) | (unsigned)(255 - c);
  };
  ull k0 = mk(p0, c0), k1 = mk(p1, c1), k2 = v2 ? mk(p2, c2) : 0ull;
  // local sort3 desc
  { ull a = k0 > k1 ? k0 : k1, b = k0 > k1 ? k1 : k0; k0 = a; k1 = b; }
  { ull a = k1 > k2 ? k1 : k2, b = k1 > k2 ? k2 : k1; k1 = a; k2 = b; }
  { ull a = k0 > k1 ? k0 : k1, b = k0 > k1 ? k1 : k0; k0 = a; k1 = b; }

  ull mykey = 0ull;
#pragma unroll
  for (int t = 0; t < NL; ++t) {
    ull g = k0;
#pragma unroll
    for (int d = 1; d < 64; d <<= 1) {
      ull o = shflx_u64(g, d);
      g = g > o ? g : o;
    }
    if (g != 0ull && k0 == g) { k0 = k1; k1 = k2; k2 = 0ull; }  // unique winner pops
    if (l == t) mykey = g;
  }

  if (l < NL) {
    float lv; int lc;
    if (mykey == 0ull) { lv = -3.4e38f; lc = 0; }
    else {
      lv = __uint_as_float((unsigned)(mykey >> 32) ^ 0x80000000u);
      lc = 255 - (int)(mykey & 0xFFu);
    }
    float* tr = tl + (size_t)j * (2 * NL);
    tr[l] = lv;
    tr[NL + l] = __int_as_float(lc);
  }
}

// fallback gemm (ws too small)
__global__ __launch_bounds__(192) void gemm_full(
    const float* __restrict__ A, const float* __restrict__ W,
    const float* __restrict__ bias, float* __restrict__ out)
{
  int c = threadIdx.x;
  int r0 = blockIdx.x * 4;
  if (c >= NC) return;
  const float* a = A + (size_t)r0 * KDIM;
  const float* wp = W + c;
  float a0 = 0.f, a1 = 0.f, a2 = 0.f, a3 = 0.f;
#pragma unroll 8
  for (int k = 0; k < KDIM; ++k) {
    float w = wp[(size_t)k * NC];
    a0 = fmaf(a[k],            w, a0);
    a1 = fmaf(a[k + KDIM],     w, a1);
    a2 = fmaf(a[k + 2 * KDIM], w, a2);
    a3 = fmaf(a[k + 3 * KDIM], w, a3);
  }
  float bb = bias[c];
  out[(size_t)(r0 + 0) * NC + c] = a0 + bb;
  out[(size_t)(r0 + 1) * NC + c] = a1 + bb;
  out[(size_t)(r0 + 2) * NC + c] = a2 + bb;
  out[(size_t)(r0 + 3) * NC + c] = a3 + bb;
}

// ---------------- Greedy NMS decode: sort-once + incremental patch rounds ----------------
// (verbatim from the passing round-5 kernel)
template <bool FAST>
__global__ __launch_bounds__(512) void decode_kernel(
    const float* __restrict__ lp, const float* __restrict__ tl,
    const float* __restrict__ boxes /* FAST: bt [NC][NB][4]; else raw */,
    float* __restrict__ commits)
{
  __shared__ ull bufA[NB];                 // 4 KB (L ping)
  __shared__ ull bufB[NB];                 // 4 KB (L pong)
  __shared__ __align__(16) int swin[NK];   // packed (row<<8)|cls
  __shared__ ull smask[NK];
  __shared__ unsigned slog[NB];            // commit log, append order
  __shared__ int cls_cnt[NC];
  __shared__ unsigned short cls_ref[NC][CMX];
  __shared__ unsigned short P[NB];         // row -> position in L
  __shared__ ull nkk[RMX];
  __shared__ int nkr[RMX], nko[RMX], nkc[RMX];
  __shared__ int m_cnt;
  __shared__ ull sred[8];
  const int j = threadIdx.x;
  const int lane = j & 63;
  const int w = j >> 6;

  auto bload = [&](int cls, int row) -> float4 {
    return FAST ? *(const float4*)(boxes + ((size_t)cls * NB + row) * 4)
                : *(const float4*)(boxes + ((size_t)row * NC + cls) * 4);
  };
  auto enc = [&](float v, int cls) -> ull {
    unsigned u = __float_as_uint(v);
    u ^= (u & 0x80000000u) ? 0xFFFFFFFFu : 0x80000000u;
    return ((ull)u << 32) | (unsigned)(0xFFFFFFFFu - (unsigned)(j * NC + cls));
  };

  if (j < NC) cls_cnt[j] = 0;

  float lv[NL]; int lc[NL];
  float m_ = 0.f, s_ = 1.f;
  const float* xr = FAST ? (lp + (size_t)j * PST) : (lp + (size_t)j * NC);

  if (FAST) {
    const float4* tl4 = (const float4*)(tl + (size_t)j * (2 * NL));
#pragma unroll
    for (int q = 0; q < NL / 4; ++q) {
      float4 v = tl4[q];
      lv[4 * q] = v.x; lv[4 * q + 1] = v.y; lv[4 * q + 2] = v.z; lv[4 * q + 3] = v.w;
    }
#pragma unroll
    for (int q = 0; q < NL / 4; ++q) {
      float4 v = tl4[NL / 4 + q];
      lc[4 * q] = __float_as_int(v.x); lc[4 * q + 1] = __float_as_int(v.y);
      lc[4 * q + 2] = __float_as_int(v.z); lc[4 * q + 3] = __float_as_int(v.w);
    }
  } else {
#pragma unroll
    for (int t = 0; t < NL; ++t) { lv[t] = -3.4e38f; lc[t] = 0; }
    m_ = xr[0];
    for (int c = 1; c < NC; ++c) m_ = fmaxf(m_, xr[c]);
    s_ = 0.f;
    for (int c = 0; c < NC; ++c) s_ += expf(xr[c] - m_);
    for (int c = 1; c < NC; ++c) {
      float v = expf(xr[c] - m_) / s_;
      if (v > lv[NL - 1]) {
        lv[NL - 1] = v; lc[NL - 1] = c;
#pragma unroll
        for (int q = NL - 1; q > 0; --q) {
          if (lv[q] > lv[q - 1]) {
            float tv = lv[q]; lv[q] = lv[q - 1]; lv[q - 1] = tv;
            int tc = lc[q]; lc[q] = lc[q - 1]; lc[q - 1] = tc;
          }
        }
      }
    }
  }

  float rowmax; int argcls; bool zstuck = false;
  if (lv[0] > 0.f) { rowmax = lv[0]; argcls = lc[0]; }
  else { rowmax = 0.f; argcls = 0; zstuck = true; }

  bool retired = false;
  int commitcls = 0;
  int ncom = 0;        // total commits
  int base = 0;        // consumed prefix of L
  int logcnt = 0;
  int flip = 0;        // 0: L=bufA, 1: L=bufB
  bool eg = false;

  auto fullsort = [&](ull key) {
    auto ce = [&](int kk, int dd) {
      ull o = shflx_u64(key, dd);
      bool km = (((j & dd) == 0) == ((j & kk) == 0));
      ull mx = key > o ? key : o, mn = key > o ? o : key;
      key = km ? mx : mn;
    };
    auto cem = [&](ull o, int kk, int dd) {
      bool km = (((j & dd) == 0) == ((j & kk) == 0));
      ull mx = key > o ? key : o, mn = key > o ? o : key;
      key = km ? mx : mn;
    };
#pragma unroll
    for (int kk = 2; kk <= 64; kk <<= 1) {
#pragma unroll
      for (int dd = kk >> 1; dd >= 1; dd >>= 1) ce(kk, dd);
    }
    __syncthreads();
    bufA[j] = key; __syncthreads();
    cem(bufA[j ^ 64], 128, 64);
#pragma unroll
    for (int dd = 32; dd >= 1; dd >>= 1) ce(128, dd);
    bufB[j] = key; __syncthreads();
    cem(bufB[j ^ 128], 256, 128);
    bufA[j] = key; __syncthreads();
    cem(bufA[j ^ 64], 256, 64);
#pragma unroll
    for (int dd = 32; dd >= 1; dd >>= 1) ce(256, dd);
    bufB[j] = key; __syncthreads();
    cem(bufB[j ^ 256], 512, 256);
    bufA[j] = key; __syncthreads();
    cem(bufA[j ^ 128], 512, 128);
    bufB[j] = key; __syncthreads();
    cem(bufB[j ^ 64], 512, 64);
#pragma unroll
    for (int dd = 32; dd >= 1; dd >>= 1) ce(512, dd);
    bufA[j] = key;                      // bufA[t] = t-th largest, exact
    if (key != 0ull) {
      unsigned f = 0xFFFFFFFFu - (unsigned)key;
      int rr = (int)(f / (unsigned)NC);
      P[rr] = (unsigned short)j;
    }
    __syncthreads();
  };

  fullsort(enc(rowmax, argcls));        // covers cls_cnt-zero visibility too

  while (ncom < NB) {
    ull* Lc = flip ? bufB : bufA;
    ull* Ln = flip ? bufA : bufB;
    int bsz = NB - base; if (bsz > NK) bsz = NK;
    int myprev = (!retired && !zstuck) ? cls_cnt[argcls] : 0;

    if (j < bsz) {
      ull k = Lc[base + j];
      int sv;
      if (k == 0ull) sv = 255;            // sentinel: class 255 never matches
      else {
        unsigned f = 0xFFFFFFFFu - (unsigned)k;
        int row = (int)(f / (unsigned)NC);
        sv = (row << 8) | (int)(f - (unsigned)row * (unsigned)NC);
      }
      swin[j] = sv; smask[j] = 0ull;
    }
    if (j == 0) m_cnt = 0;
    if (w == 7) {
      // rounds probe: 2 single-bank LDS reads per bulk round
      volatile int* pb = (volatile int*)slog;
      int t0 = pb[(lane & 31) * 16];
      int t1 = pb[(lane & 31) * 16 + 1];
      asm volatile("" :: "v"(t0), "v"(t1));
    }
    __syncthreads();   // B1

    // ---- conflict detection among batch (s<t pairs, 8 per thread) ----
    {
      int t = j >> 3, sb = (j & 7) * 8;
      if (t < bsz) {
        int pT = swin[t];
        int cT = pT & 255, rT = pT >> 8;
        int4 sA4 = *(const int4*)&swin[sb];
        int4 sB4 = *(const int4*)&swin[sb + 4];
        int ss[8] = {sA4.x, sA4.y, sA4.z, sA4.w, sB4.x, sB4.y, sB4.z, sB4.w};
        ull myc = 0ull;
#pragma unroll
        for (int u = 0; u < 8; ++u) {
          int s = sb + u;
          if (s < t && (ss[u] & 255) == cT && cT != 255) {   // rare class match
            float4 bs = bload(cT, ss[u] >> 8);
            float4 btx = bload(cT, rT);
            if (overlap_ge(bs, btx)) myc |= (1ull << s);
          }
        }
        if (myc) atomicOr(&smask[t], myc);
      }
    }
    __syncthreads();   // B2

    // ---- prefix-validity: fast path (no conflicts) or full chain ----
    int p;
    {
      ull kv = (lane < bsz) ? Lc[base + lane] : 0ull;
      ull sm = (lane < bsz) ? smask[lane] : 0ull;
      ull okm = __ballot((lane < bsz) && ((unsigned)(kv >> 32) > 0x80000000u));
      ull anyc = __ballot(sm != 0ull);
      if (!(okm & 1ull)) {
        p = 0; eg = true;
      } else if (anyc == 0ull) {
        ull inv = ~okm;
        if (inv == 0ull) p = 64;
        else p = (int)__ffsll((long long)inv) - 1;   // run of 1s from bit0; <= bsz
        eg = (p < bsz);                              // stopped by value (no conflicts)
      } else {
        ull valid = 1ull; p = 1;
#pragma unroll
        for (int t = 1; t < NK; ++t) {
          ull cm = readlane_u64(sm, t);
          bool ok = (p == t) && ((okm >> t) & 1ull) && ((cm & valid) == 0ull);
          if (ok) { valid |= (1ull << t); p = t + 1; }
        }
        eg = (p < bsz) && !((okm >> p) & 1ull);
      }
    }

    // ---- append commits to log + per-class index ----
    if (j < p) {
      unsigned e = (unsigned)swin[j];
      slog[logcnt + j] = e;
      int c = (int)(e & 255u);
      int old = atomicAdd(&cls_cnt[c], 1);
      if (old < CMX) cls_ref[c][old] = (unsigned short)(logcnt + j);
    }
    __syncthreads();   // B3
    logcnt += p;

    // ---- O(1) retire / suppression detect, pull on suppression ----
    bool chg = false; ull nkey = 0ull;
    if (!retired) {
      int mypos = (int)P[j];
      if (mypos >= base && mypos < base + p) {
        retired = true; commitcls = argcls;          // my entry just committed
      } else if (!zstuck) {
        bool supp = false;
        int nowc = cls_cnt[argcls];
        if (nowc > myprev) {                         // new same-class commits
          float4 ob = bload(argcls, j);
          if (nowc <= CMX) {
#pragma unroll 1
            for (int q = myprev; q < nowc && !supp; ++q) {
              unsigned e = slog[cls_ref[argcls][q]];
              if (overlap_ge(bload(argcls, (int)(e >> 8)), ob)) supp = true;
            }
          } else {                                   // overflow: scan this round's appends
#pragma unroll 1
            for (int q = logcnt - p; q < logcnt && !supp; ++q) {
              unsigned e = slog[q];
              if ((int)(e & 255u) == argcls &&
                  overlap_ge(bload(argcls, (int)(e >> 8)), ob)) supp = true;
            }
          }
        }
        if (supp) {
          // pull next candidate from cache, validated vs FULL commit history
          bool found = false;
#pragma unroll 1
          for (int t = 0; t < NL && !found; ++t) {
            if (!(lv[t] > 0.f)) break;
            int c = lc[t];
            int cnt = cls_cnt[c];
            bool bad = false;
            if (cnt > 0) {
              float4 ob2 = bload(c, j);
              if (cnt <= CMX) {
                for (int q = 0; q < cnt && !bad; ++q) {
                  unsigned e = slog[cls_ref[c][q]];
                  if (overlap_ge(bload(c, (int)(e >> 8)), ob2)) bad = true;
                }
              } else {
                for (int q = 0; q < logcnt && !bad; ++q) {
                  unsigned e = slog[q];
                  if ((int)(e & 255u) == c &&
                      overlap_ge(bload(c, (int)(e >> 8)), ob2)) bad = true;
                }
              }
            }
            if (!bad) { rowmax = lv[t]; argcls = c; found = true; }
          }
          if (!found) {
            // cache exhausted: rebuild mask from log, rescan stored probs
            unsigned msk[5] = {0, 0, 0, 0, 0};
            for (int q = 0; q < logcnt; ++q) {
              unsigned e = slog[q];
              int c = (int)(e & 255u), r = (int)(e >> 8);
              if (r != j && !mbit(msk, c)) {
                if (overlap_ge(bload(c, r), bload(c, j))) {
#pragma unroll
                  for (int k5b = 0; k5b < 5; ++k5b)
                    if (k5b == (c >> 5)) msk[k5b] |= (1u << (c & 31));
                }
              }
            }
            float bm = -3.4e38f; int ba = 0;
            if (FAST) {
              for (int c4 = 0; c4 < PST / 4; ++c4) {
                float4 v4 = *(const float4*)(xr + c4 * 4);
                int c = c4 * 4;
                float vals[4] = {v4.x, v4.y, v4.z, v4.w};
#pragma unroll
                for (int u = 0; u < 4; ++u) {
                  int cc = c + u;
                  float v = mbit(msk, cc) ? 0.f : vals[u];
                  if (v > bm) { bm = v; ba = cc; }
                }
              }
            } else {
              for (int c = 0; c < NC; ++c) {
                float v;
                if (c == 0) v = 0.f;
                else v = mbit(msk, c) ? 0.f : (expf(xr[c] - m_) / s_);
                if (v > bm) { bm = v; ba = c; }
              }
            }
            rowmax = bm; argcls = ba;
            if (!(bm > 0.f)) zstuck = true;
          }
          chg = true; nkey = enc(rowmax, argcls);
        }
      }
    }
    if (chg) {
      int i = atomicAdd(&m_cnt, 1);
      if (i < RMX) { nkk[i] = nkey; nkr[i] = j; nko[i] = (int)P[j]; nkc[i] = 0; }
    }
    __syncthreads();   // B4

    int m = m_cnt;
    base += p; ncom += p;
    if (eg) break;
    if (m == 0) continue;                   // L untouched beyond base

    if (m <= RMX) {
      // ---- merge-by-rank reinsert: remove old slots, insert new keys ----
      bool haveslot = (j >= base);
      ull myk = 0ull; bool isrem = false; int rb_ = 0;
      if (haveslot) {
        myk = Lc[j];
#pragma unroll 1
        for (int i = 0; i < m; ++i) { int op = nko[i]; isrem |= (op == j); rb_ += (op < j) ? 1 : 0; }
      }
#pragma unroll 1
      for (int i = 0; i < m; ++i) {
        ull b = __ballot(haveslot && !isrem && (myk > nkk[i]));
        if (lane == 0 && b) atomicAdd(&nkc[i], (int)__popcll(b));
      }
      if (haveslot && !isrem) {
        int nb_ = 0;
#pragma unroll 1
        for (int i = 0; i < m; ++i) nb_ += (nkk[i] > myk) ? 1 : 0;
        int np = j - rb_ + nb_;
        Ln[np] = myk;
        if (myk != 0ull) {
          unsigned f = 0xFFFFFFFFu - (unsigned)myk;
          int rr = (int)(f / (unsigned)NC);
          P[rr] = (unsigned short)np;
        }
      }
      __syncthreads(); // B5: nkc complete, live writes done
      if (j < m) {
        ull ki = nkk[j]; int gt = 0;
#pragma unroll 1
        for (int i = 0; i < m; ++i) gt += (nkk[i] > ki) ? 1 : 0;
        int np = base + nkc[j] + gt;
        Ln[np] = ki;
        P[nkr[j]] = (unsigned short)np;
      }
      __syncthreads(); // B6
      flip ^= 1;
    } else {
      // ---- overflow fallback: exact full resort of live keys (retired=sentinel 0) ----
      fullsort(retired ? 0ull : enc(rowmax, argcls));
      flip = 0;
      base = 0;
    }
  }

  // ================== endgame (value exhaustion; exact recon + argmax loop) ==================
  if (ncom < NB) {
    unsigned msk[5] = {0, 0, 0, 0, 0};
    int post_min = INT_MAX;
    bool ret = false; int ccls = commitcls;
    for (int q = 0; q < logcnt; ++q) {
      unsigned e = slog[q];
      int r = (int)(e >> 8), c = (int)(e & 255u);
      if (j == r) { ret = true; ccls = c; post_min = INT_MAX; }
      else {
        if (overlap_ge(bload(c, r), bload(c, j))) {
          if (ret) post_min = (c < post_min) ? c : post_min;
          else {
#pragma unroll
            for (int k5b = 0; k5b < 5; ++k5b) if (k5b == (c >> 5)) msk[k5b] |= (1u << (c & 31));
          }
        }
      }
    }
    retired = ret; if (ret) commitcls = ccls;
    if (retired) {
      rowmax = (post_min != INT_MAX) ? 0.0f : -1.0f;
      argcls = (post_min != INT_MAX) ? post_min : 0;
    } else {
      float bm = -3.4e38f; int ba = 0;
      if (FAST) {
        for (int c4 = 0; c4 < PST / 4; ++c4) {
          float4 v4 = *(const float4*)(xr + c4 * 4);
          int c = c4 * 4;
          float vals[4] = {v4.x, v4.y, v4.z, v4.w};
#pragma unroll
          for (int u = 0; u < 4; ++u) {
            int cc = c + u;
            float v = mbit(msk, cc) ? 0.f : vals[u];
            if (v > bm) { bm = v; ba = cc; }
          }
        }
      } else {
        for (int c = 0; c < NC; ++c) {
          float v;
          if (c == 0) v = 0.f;
          else v = mbit(msk, c) ? 0.f : (expf(xr[c] - m_) / s_);
          if (v > bm) { bm = v; ba = c; }
        }
      }
      rowmax = bm; argcls = ba;
    }

    while (ncom < NB) {
      ull k = enc(rowmax, argcls);
#pragma unroll
      for (int dd = 32; dd >= 1; dd >>= 1) {
        ull o = shflx_u64(k, dd);
        k = k > o ? k : o;
      }
      __syncthreads();
      if (lane == 0) sred[w] = k;
      if (w == 7) {
        volatile int* pb = (volatile int*)slog;    // endgame probe: 1 read/iter
        int t0 = pb[(lane & 31) * 16];
        asm volatile("" :: "v"(t0));
      }
      __syncthreads();
      ull g = sred[0];
#pragma unroll
      for (int q = 1; q < 8; ++q) { ull t = sred[q]; g = g > t ? g : t; }
      unsigned f = 0xFFFFFFFFu - (unsigned)g;
      int row = (int)(f / (unsigned)NC);
      int cls = (int)(f - (unsigned)row * (unsigned)NC);
      float4 cb = bload(cls, row);
      float4 ob = bload(cls, j);
      if (j == row) {
        retired = true; commitcls = cls; post_min = INT_MAX;
        rowmax = -1.0f; argcls = 0;
      } else if (overlap_ge(cb, ob)) {
        if (retired) {
          post_min = (cls < post_min) ? cls : post_min;   // resurrect -1 -> 0.0 @ min cls
          rowmax = 0.0f; argcls = post_min;
        }
        // live rows here are all-zero rows: another 0.0 entry never moves their argmax
      }
      ++ncom;
    }
  }

  commits[j] = (float)commitcls;
}

extern "C" void kernel_launch(void* const* d_in, const int* in_sizes, int n_in,
                              void* d_out, int out_size, void* d_ws, size_t ws_size,
                              hipStream_t stream) {
  const float* A     = (const float*)d_in[0];   // obj_fmap [512,4096]
  const float* boxes = (const float*)d_in[1];   // boxes_per_cls [512,151,4]
  const float* W     = (const float*)d_in[2];   // [4096,151]
  const float* bias  = (const float*)d_in[3];   // [151]
  float* out = (float*)d_out;                   // [512*151] obj_dists ++ [512] commits

  const size_t np = (size_t)KS * NB * PST;      // part
  const size_t nl = (size_t)NB * PST;           // lp
  const size_t nt = (size_t)NB * (2 * NL);      // tl
  const size_t nb = (size_t)NC * NB * 4;        // bt
  const size_t need = (np + nl + nt + nb) * 4;

  if (ws_size >= need) {
    float* part = (float*)d_ws;
    float* lp   = part + np;
    float* tl   = lp + nl;
    float* bt   = tl + nt;
    gemm_fused<<<TPB_GEMM + NTR, 192, 0, stream>>>(A, W, boxes, part, bt);
    prep_kernel<<<NB, 64, 0, stream>>>(part, bias, out, lp, tl);
    decode_kernel<true><<<1, NB, 0, stream>>>(lp, tl, bt, out + NB * NC);
  } else {
    gemm_full<<<NB / 4, 192, 0, stream>>>(A, W, bias, out);
    decode_kernel<false><<<1, NB, 0, stream>>>(out, nullptr, boxes, out + NB * NC);
  }
}

// Round 7
// 137.278 us; speedup vs baseline: 3.0300x; 1.1680x over previous
//
#include <hip/hip_runtime.h>
#include <limits.h>

#pragma clang fp contract(off)

#define NB 512
#define NC 151
#define KDIM 4096
#define KS 8
#define KCH (KDIM/KS)      // 512
#define GRB 4              // gemm rows per block (4x blocks vs GRB=16 -> occupancy)
#define PST 152            // padded row stride (floats), 16B-aligned rows
#define NK 64              // commits per round (batch)
#define NL 16              // cached top-list depth per row
#define CMX 16             // per-class log index slots (overflow -> filtered scan)
#define RMX 64             // max re-inserted keys per round (overflow -> full resort)
#define NMS_TH 0.3f

typedef unsigned long long ull;

// exact reference IoU arithmetic (fp contract off file-wide)
__device__ __forceinline__ bool overlap_ge(const float4& c, const float4& o) {
  float areaC = (c.z - c.x + 1.0f) * (c.w - c.y + 1.0f);
  float areaJ = (o.z - o.x + 1.0f) * (o.w - o.y + 1.0f);
  float iw = fminf(c.z, o.z) - fmaxf(c.x, o.x) + 1.0f;
  float ih = fminf(c.w, o.w) - fmaxf(c.y, o.y) + 1.0f;
  iw = fmaxf(iw, 0.0f); ih = fmaxf(ih, 0.0f);
  float inter = iw * ih;
  float uni = areaC + areaJ - inter;
  return inter / uni >= NMS_TH;
}

__device__ __forceinline__ bool mbit(const unsigned m[5], int c) {
  bool r = false;
#pragma unroll
  for (int k = 0; k < 5; ++k) r = (k == (c >> 5)) ? (((m[k] >> (c & 31)) & 1u) != 0) : r;
  return r;
}

// 64-bit shuffle-xor across the full wave64
__device__ __forceinline__ ull shflx_u64(ull v, int m) {
  int lo = (int)(unsigned)(v & 0xFFFFFFFFull);
  int hi = (int)(unsigned)(v >> 32);
  lo = __shfl_xor(lo, m, 64);
  hi = __shfl_xor(hi, m, 64);
  return ((ull)(unsigned)hi << 32) | (unsigned)lo;
}

__device__ __forceinline__ ull readlane_u64(ull v, int t) {
  int lo = __builtin_amdgcn_readlane((int)(unsigned)(v & 0xFFFFFFFFull), t);
  int hi = __builtin_amdgcn_readlane((int)(unsigned)(v >> 32), t);
  return ((ull)(unsigned)hi << 32) | (unsigned)lo;
}

// ---------------- kernel 1: fused GEMM split-K partials + boxes transpose ----------------
#define TPB_GEMM ((NB / GRB) * KS)    // 1024
#define NTR ((NB * NC + 191) / 192)   // 403
__global__ __launch_bounds__(192) void gemm_fused(
    const float* __restrict__ A, const float* __restrict__ W,
    const float* __restrict__ boxes, float* __restrict__ part, float* __restrict__ bt)
{
  if (blockIdx.x >= TPB_GEMM) {
    int i = (blockIdx.x - TPB_GEMM) * 192 + threadIdx.x;
    if (i < NB * NC) {
      int r = i / NC, c = i - r * NC;
      float4 v = *(const float4*)(boxes + (size_t)i * 4);      // coalesced read
      *(float4*)(bt + ((size_t)c * NB + r) * 4) = v;           // scattered write (once)
    }
    return;
  }
  __shared__ float sA[GRB * KCH];  // 8 KB
  int rb = blockIdx.x >> 3, ks = blockIdx.x & 7;
  const float* Ab = A + (size_t)rb * GRB * KDIM + (size_t)ks * KCH;
  for (int i = threadIdx.x; i < GRB * (KCH / 4); i += 192) {
    int r = i >> 7;            // KCH/4 = 128
    int k4 = i & 127;
    *(float4*)(sA + r * KCH + k4 * 4) = *(const float4*)(Ab + (size_t)r * KDIM + k4 * 4);
  }
  __syncthreads();
  int c = threadIdx.x;
  if (c < NC) {
    const float* wp = W + (size_t)ks * KCH * NC + c;
    float acc[GRB];
#pragma unroll
    for (int r = 0; r < GRB; ++r) acc[r] = 0.f;
    float w0 = wp[0], w1 = wp[NC], w2 = wp[2 * NC], w3 = wp[3 * NC];
    for (int k4 = 0; k4 < KCH / 4; ++k4) {
      int kn = (k4 + 1 < KCH / 4) ? (k4 + 1) : k4;     // clamp: re-read last (no OOB)
      const float* q = wp + (size_t)(4 * kn) * NC;
      float n0 = q[0], n1 = q[NC], n2 = q[2 * NC], n3 = q[3 * NC];
#pragma unroll
      for (int r = 0; r < GRB; ++r) {
        float4 a = *(const float4*)(sA + r * KCH + k4 * 4);  // broadcast read
        acc[r] = fmaf(a.x, w0, acc[r]);
        acc[r] = fmaf(a.y, w1, acc[r]);
        acc[r] = fmaf(a.z, w2, acc[r]);
        acc[r] = fmaf(a.w, w3, acc[r]);
      }
      w0 = n0; w1 = n1; w2 = n2; w3 = n3;
    }
    float* o = part + ((size_t)ks * NB + (size_t)rb * GRB) * PST + c;
#pragma unroll
    for (int r = 0; r < GRB; ++r) o[(size_t)r * PST] = acc[r];
  }
}

// ---------------- kernel 2: wave-per-row reduce + obj_dists + softmax + top-16 ----------------
// (verbatim from the passing round-6 kernel)
__global__ __launch_bounds__(64) void prep_kernel(
    const float* __restrict__ part, const float* __restrict__ bias,
    float* __restrict__ out, float* __restrict__ lp, float* __restrict__ tl)
{
  const int j = blockIdx.x;        // row
  const int l = threadIdx.x;       // lane
  const int c0 = l, c1 = l + 64, c2 = l + 128;
  const bool v2 = (c2 < NC);       // c0,c1 always valid (<=127 < 151)

  float x0 = 0.f, x1 = 0.f, x2 = 0.f;
#pragma unroll
  for (int ks = 0; ks < KS; ++ks) {      // same ks accumulation order as before
    const float* pb = part + ((size_t)ks * NB + j) * PST;
    x0 += pb[c0];
    x1 += pb[c1];
    if (v2) x2 += pb[c2];
  }
  x0 += bias[c0];
  x1 += bias[c1];
  if (v2) x2 += bias[c2]; else x2 = -3.4e38f;   // pad: exp -> 0

  float* orow = out + (size_t)j * NC;
  orow[c0] = x0;
  orow[c1] = x1;
  if (v2) orow[c2] = x2;

  // wave max (exact)
  float m_ = fmaxf(x0, fmaxf(x1, x2));
#pragma unroll
  for (int d = 1; d < 64; d <<= 1) m_ = fmaxf(m_, __shfl_xor(m_, d, 64));

  float e0 = expf(x0 - m_), e1 = expf(x1 - m_), e2 = expf(x2 - m_);  // pad e2=0
  float s_ = e0 + e1 + e2;
#pragma unroll
  for (int d = 1; d < 64; d <<= 1) s_ += __shfl_xor(s_, d, 64);

  float p0 = (c0 == 0) ? 0.f : e0 / s_;
  float p1 = e1 / s_;
  float p2 = e2 / s_;                    // pad -> 0/s_ = 0

  float* pr = lp + (size_t)j * PST;
  pr[c0] = p0;
  pr[c1] = p1;
  if (c2 < PST) pr[c2] = v2 ? p2 : 0.f;  // idx 151 pad -> 0

  // ---- top-16 via 16 wave-argmax pops ----
  auto mk = [&](float p, int c) -> ull {
    if (!(p > 0.f)) return 0ull;
    unsigned u = __float_as_uint(p) ^ 0x80000000u;   // p>0: orderable = set sign bit
    return ((ull)u << 32) | (unsigned)(255 - c);
  };
  ull k0 = mk(p0, c0), k1 = mk(p1, c1), k2 = v2 ? mk(p2, c2) : 0ull;
  // local sort3 desc
  { ull a = k0 > k1 ? k0 : k1, b = k0 > k1 ? k1 : k0; k0 = a; k1 = b; }
  { ull a = k1 > k2 ? k1 : k2, b = k1 > k2 ? k2 : k1; k1 = a; k2 = b; }
  { ull a = k0 > k1 ? k0 : k1, b = k0 > k1 ? k1 : k0; k0 = a; k1 = b; }

  ull mykey = 0ull;
#pragma unroll
  for (int t = 0; t < NL; ++t) {
    ull g = k0;
#pragma unroll
    for (int d = 1; d < 64; d <<= 1) {
      ull o = shflx_u64(g, d);
      g = g > o ? g : o;
    }
    if (g != 0ull && k0 == g) { k0 = k1; k1 = k2; k2 = 0ull; }  // unique winner pops
    if (l == t) mykey = g;
  }

  if (l < NL) {
    float lv; int lc;
    if (mykey == 0ull) { lv = -3.4e38f; lc = 0; }
    else {
      lv = __uint_as_float((unsigned)(mykey >> 32) ^ 0x80000000u);
      lc = 255 - (int)(mykey & 0xFFu);
    }
    float* tr = tl + (size_t)j * (2 * NL);
    tr[l] = lv;
    tr[NL + l] = __int_as_float(lc);
  }
}

// fallback gemm (ws too small)
__global__ __launch_bounds__(192) void gemm_full(
    const float* __restrict__ A, const float* __restrict__ W,
    const float* __restrict__ bias, float* __restrict__ out)
{
  int c = threadIdx.x;
  int r0 = blockIdx.x * 4;
  if (c >= NC) return;
  const float* a = A + (size_t)r0 * KDIM;
  const float* wp = W + c;
  float a0 = 0.f, a1 = 0.f, a2 = 0.f, a3 = 0.f;
#pragma unroll 8
  for (int k = 0; k < KDIM; ++k) {
    float w = wp[(size_t)k * NC];
    a0 = fmaf(a[k],            w, a0);
    a1 = fmaf(a[k + KDIM],     w, a1);
    a2 = fmaf(a[k + 2 * KDIM], w, a2);
    a3 = fmaf(a[k + 3 * KDIM], w, a3);
  }
  float bb = bias[c];
  out[(size_t)(r0 + 0) * NC + c] = a0 + bb;
  out[(size_t)(r0 + 1) * NC + c] = a1 + bb;
  out[(size_t)(r0 + 2) * NC + c] = a2 + bb;
  out[(size_t)(r0 + 3) * NC + c] = a3 + bb;
}

// ---------------- Greedy NMS decode: sort-once + incremental patch rounds ----------------
// (verbatim from the passing round-5/6 kernel)
template <bool FAST>
__global__ __launch_bounds__(512) void decode_kernel(
    const float* __restrict__ lp, const float* __restrict__ tl,
    const float* __restrict__ boxes /* FAST: bt [NC][NB][4]; else raw */,
    float* __restrict__ commits)
{
  __shared__ ull bufA[NB];                 // 4 KB (L ping)
  __shared__ ull bufB[NB];                 // 4 KB (L pong)
  __shared__ __align__(16) int swin[NK];   // packed (row<<8)|cls
  __shared__ ull smask[NK];
  __shared__ unsigned slog[NB];            // commit log, append order
  __shared__ int cls_cnt[NC];
  __shared__ unsigned short cls_ref[NC][CMX];
  __shared__ unsigned short P[NB];         // row -> position in L
  __shared__ ull nkk[RMX];
  __shared__ int nkr[RMX], nko[RMX], nkc[RMX];
  __shared__ int m_cnt;
  __shared__ ull sred[8];
  const int j = threadIdx.x;
  const int lane = j & 63;
  const int w = j >> 6;

  auto bload = [&](int cls, int row) -> float4 {
    return FAST ? *(const float4*)(boxes + ((size_t)cls * NB + row) * 4)
                : *(const float4*)(boxes + ((size_t)row * NC + cls) * 4);
  };
  auto enc = [&](float v, int cls) -> ull {
    unsigned u = __float_as_uint(v);
    u ^= (u & 0x80000000u) ? 0xFFFFFFFFu : 0x80000000u;
    return ((ull)u << 32) | (unsigned)(0xFFFFFFFFu - (unsigned)(j * NC + cls));
  };

  if (j < NC) cls_cnt[j] = 0;

  float lv[NL]; int lc[NL];
  float m_ = 0.f, s_ = 1.f;
  const float* xr = FAST ? (lp + (size_t)j * PST) : (lp + (size_t)j * NC);

  if (FAST) {
    const float4* tl4 = (const float4*)(tl + (size_t)j * (2 * NL));
#pragma unroll
    for (int q = 0; q < NL / 4; ++q) {
      float4 v = tl4[q];
      lv[4 * q] = v.x; lv[4 * q + 1] = v.y; lv[4 * q + 2] = v.z; lv[4 * q + 3] = v.w;
    }
#pragma unroll
    for (int q = 0; q < NL / 4; ++q) {
      float4 v = tl4[NL / 4 + q];
      lc[4 * q] = __float_as_int(v.x); lc[4 * q + 1] = __float_as_int(v.y);
      lc[4 * q + 2] = __float_as_int(v.z); lc[4 * q + 3] = __float_as_int(v.w);
    }
  } else {
#pragma unroll
    for (int t = 0; t < NL; ++t) { lv[t] = -3.4e38f; lc[t] = 0; }
    m_ = xr[0];
    for (int c = 1; c < NC; ++c) m_ = fmaxf(m_, xr[c]);
    s_ = 0.f;
    for (int c = 0; c < NC; ++c) s_ += expf(xr[c] - m_);
    for (int c = 1; c < NC; ++c) {
      float v = expf(xr[c] - m_) / s_;
      if (v > lv[NL - 1]) {
        lv[NL - 1] = v; lc[NL - 1] = c;
#pragma unroll
        for (int q = NL - 1; q > 0; --q) {
          if (lv[q] > lv[q - 1]) {
            float tv = lv[q]; lv[q] = lv[q - 1]; lv[q - 1] = tv;
            int tc = lc[q]; lc[q] = lc[q - 1]; lc[q - 1] = tc;
          }
        }
      }
    }
  }

  float rowmax; int argcls; bool zstuck = false;
  if (lv[0] > 0.f) { rowmax = lv[0]; argcls = lc[0]; }
  else { rowmax = 0.f; argcls = 0; zstuck = true; }

  bool retired = false;
  int commitcls = 0;
  int ncom = 0;        // total commits
  int base = 0;        // consumed prefix of L
  int logcnt = 0;
  int flip = 0;        // 0: L=bufA, 1: L=bufB
  bool eg = false;

  auto fullsort = [&](ull key) {
    auto ce = [&](int kk, int dd) {
      ull o = shflx_u64(key, dd);
      bool km = (((j & dd) == 0) == ((j & kk) == 0));
      ull mx = key > o ? key : o, mn = key > o ? o : key;
      key = km ? mx : mn;
    };
    auto cem = [&](ull o, int kk, int dd) {
      bool km = (((j & dd) == 0) == ((j & kk) == 0));
      ull mx = key > o ? key : o, mn = key > o ? o : key;
      key = km ? mx : mn;
    };
#pragma unroll
    for (int kk = 2; kk <= 64; kk <<= 1) {
#pragma unroll
      for (int dd = kk >> 1; dd >= 1; dd >>= 1) ce(kk, dd);
    }
    __syncthreads();
    bufA[j] = key; __syncthreads();
    cem(bufA[j ^ 64], 128, 64);
#pragma unroll
    for (int dd = 32; dd >= 1; dd >>= 1) ce(128, dd);
    bufB[j] = key; __syncthreads();
    cem(bufB[j ^ 128], 256, 128);
    bufA[j] = key; __syncthreads();
    cem(bufA[j ^ 64], 256, 64);
#pragma unroll
    for (int dd = 32; dd >= 1; dd >>= 1) ce(256, dd);
    bufB[j] = key; __syncthreads();
    cem(bufB[j ^ 256], 512, 256);
    bufA[j] = key; __syncthreads();
    cem(bufA[j ^ 128], 512, 128);
    bufB[j] = key; __syncthreads();
    cem(bufB[j ^ 64], 512, 64);
#pragma unroll
    for (int dd = 32; dd >= 1; dd >>= 1) ce(512, dd);
    bufA[j] = key;                      // bufA[t] = t-th largest, exact
    if (key != 0ull) {
      unsigned f = 0xFFFFFFFFu - (unsigned)key;
      int rr = (int)(f / (unsigned)NC);
      P[rr] = (unsigned short)j;
    }
    __syncthreads();
  };

  fullsort(enc(rowmax, argcls));        // covers cls_cnt-zero visibility too

  while (ncom < NB) {
    ull* Lc = flip ? bufB : bufA;
    ull* Ln = flip ? bufA : bufB;
    int bsz = NB - base; if (bsz > NK) bsz = NK;
    int myprev = (!retired && !zstuck) ? cls_cnt[argcls] : 0;

    if (j < bsz) {
      ull k = Lc[base + j];
      int sv;
      if (k == 0ull) sv = 255;            // sentinel: class 255 never matches
      else {
        unsigned f = 0xFFFFFFFFu - (unsigned)k;
        int row = (int)(f / (unsigned)NC);
        sv = (row << 8) | (int)(f - (unsigned)row * (unsigned)NC);
      }
      swin[j] = sv; smask[j] = 0ull;
    }
    if (j == 0) m_cnt = 0;
    if (w == 7) {
      // rounds probe: 2 single-bank LDS reads per bulk round
      volatile int* pb = (volatile int*)slog;
      int t0 = pb[(lane & 31) * 16];
      int t1 = pb[(lane & 31) * 16 + 1];
      asm volatile("" :: "v"(t0), "v"(t1));
    }
    __syncthreads();   // B1

    // ---- conflict detection among batch (s<t pairs, 8 per thread) ----
    {
      int t = j >> 3, sb = (j & 7) * 8;
      if (t < bsz) {
        int pT = swin[t];
        int cT = pT & 255, rT = pT >> 8;
        int4 sA4 = *(const int4*)&swin[sb];
        int4 sB4 = *(const int4*)&swin[sb + 4];
        int ss[8] = {sA4.x, sA4.y, sA4.z, sA4.w, sB4.x, sB4.y, sB4.z, sB4.w};
        ull myc = 0ull;
#pragma unroll
        for (int u = 0; u < 8; ++u) {
          int s = sb + u;
          if (s < t && (ss[u] & 255) == cT && cT != 255) {   // rare class match
            float4 bs = bload(cT, ss[u] >> 8);
            float4 btx = bload(cT, rT);
            if (overlap_ge(bs, btx)) myc |= (1ull << s);
          }
        }
        if (myc) atomicOr(&smask[t], myc);
      }
    }
    __syncthreads();   // B2

    // ---- prefix-validity: fast path (no conflicts) or full chain ----
    int p;
    {
      ull kv = (lane < bsz) ? Lc[base + lane] : 0ull;
      ull sm = (lane < bsz) ? smask[lane] : 0ull;
      ull okm = __ballot((lane < bsz) && ((unsigned)(kv >> 32) > 0x80000000u));
      ull anyc = __ballot(sm != 0ull);
      if (!(okm & 1ull)) {
        p = 0; eg = true;
      } else if (anyc == 0ull) {
        ull inv = ~okm;
        if (inv == 0ull) p = 64;
        else p = (int)__ffsll((long long)inv) - 1;   // run of 1s from bit0; <= bsz
        eg = (p < bsz);                              // stopped by value (no conflicts)
      } else {
        ull valid = 1ull; p = 1;
#pragma unroll
        for (int t = 1; t < NK; ++t) {
          ull cm = readlane_u64(sm, t);
          bool ok = (p == t) && ((okm >> t) & 1ull) && ((cm & valid) == 0ull);
          if (ok) { valid |= (1ull << t); p = t + 1; }
        }
        eg = (p < bsz) && !((okm >> p) & 1ull);
      }
    }

    // ---- append commits to log + per-class index ----
    if (j < p) {
      unsigned e = (unsigned)swin[j];
      slog[logcnt + j] = e;
      int c = (int)(e & 255u);
      int old = atomicAdd(&cls_cnt[c], 1);
      if (old < CMX) cls_ref[c][old] = (unsigned short)(logcnt + j);
    }
    __syncthreads();   // B3
    logcnt += p;

    // ---- O(1) retire / suppression detect, pull on suppression ----
    bool chg = false; ull nkey = 0ull;
    if (!retired) {
      int mypos = (int)P[j];
      if (mypos >= base && mypos < base + p) {
        retired = true; commitcls = argcls;          // my entry just committed
      } else if (!zstuck) {
        bool supp = false;
        int nowc = cls_cnt[argcls];
        if (nowc > myprev) {                         // new same-class commits
          float4 ob = bload(argcls, j);
          if (nowc <= CMX) {
#pragma unroll 1
            for (int q = myprev; q < nowc && !supp; ++q) {
              unsigned e = slog[cls_ref[argcls][q]];
              if (overlap_ge(bload(argcls, (int)(e >> 8)), ob)) supp = true;
            }
          } else {                                   // overflow: scan this round's appends
#pragma unroll 1
            for (int q = logcnt - p; q < logcnt && !supp; ++q) {
              unsigned e = slog[q];
              if ((int)(e & 255u) == argcls &&
                  overlap_ge(bload(argcls, (int)(e >> 8)), ob)) supp = true;
            }
          }
        }
        if (supp) {
          // pull next candidate from cache, validated vs FULL commit history
          bool found = false;
#pragma unroll 1
          for (int t = 0; t < NL && !found; ++t) {
            if (!(lv[t] > 0.f)) break;
            int c = lc[t];
            int cnt = cls_cnt[c];
            bool bad = false;
            if (cnt > 0) {
              float4 ob2 = bload(c, j);
              if (cnt <= CMX) {
                for (int q = 0; q < cnt && !bad; ++q) {
                  unsigned e = slog[cls_ref[c][q]];
                  if (overlap_ge(bload(c, (int)(e >> 8)), ob2)) bad = true;
                }
              } else {
                for (int q = 0; q < logcnt && !bad; ++q) {
                  unsigned e = slog[q];
                  if ((int)(e & 255u) == c &&
                      overlap_ge(bload(c, (int)(e >> 8)), ob2)) bad = true;
                }
              }
            }
            if (!bad) { rowmax = lv[t]; argcls = c; found = true; }
          }
          if (!found) {
            // cache exhausted: rebuild mask from log, rescan stored probs
            unsigned msk[5] = {0, 0, 0, 0, 0};
            for (int q = 0; q < logcnt; ++q) {
              unsigned e = slog[q];
              int c = (int)(e & 255u), r = (int)(e >> 8);
              if (r != j && !mbit(msk, c)) {
                if (overlap_ge(bload(c, r), bload(c, j))) {
#pragma unroll
                  for (int k5b = 0; k5b < 5; ++k5b)
                    if (k5b == (c >> 5)) msk[k5b] |= (1u << (c & 31));
                }
              }
            }
            float bm = -3.4e38f; int ba = 0;
            if (FAST) {
              for (int c4 = 0; c4 < PST / 4; ++c4) {
                float4 v4 = *(const float4*)(xr + c4 * 4);
                int c = c4 * 4;
                float vals[4] = {v4.x, v4.y, v4.z, v4.w};
#pragma unroll
                for (int u = 0; u < 4; ++u) {
                  int cc = c + u;
                  float v = mbit(msk, cc) ? 0.f : vals[u];
                  if (v > bm) { bm = v; ba = cc; }
                }
              }
            } else {
              for (int c = 0; c < NC; ++c) {
                float v;
                if (c == 0) v = 0.f;
                else v = mbit(msk, c) ? 0.f : (expf(xr[c] - m_) / s_);
                if (v > bm) { bm = v; ba = c; }
              }
            }
            rowmax = bm; argcls = ba;
            if (!(bm > 0.f)) zstuck = true;
          }
          chg = true; nkey = enc(rowmax, argcls);
        }
      }
    }
    if (chg) {
      int i = atomicAdd(&m_cnt, 1);
      if (i < RMX) { nkk[i] = nkey; nkr[i] = j; nko[i] = (int)P[j]; nkc[i] = 0; }
    }
    __syncthreads();   // B4

    int m = m_cnt;
    base += p; ncom += p;
    if (eg) break;
    if (m == 0) continue;                   // L untouched beyond base

    if (m <= RMX) {
      // ---- merge-by-rank reinsert: remove old slots, insert new keys ----
      bool haveslot = (j >= base);
      ull myk = 0ull; bool isrem = false; int rb_ = 0;
      if (haveslot) {
        myk = Lc[j];
#pragma unroll 1
        for (int i = 0; i < m; ++i) { int op = nko[i]; isrem |= (op == j); rb_ += (op < j) ? 1 : 0; }
      }
#pragma unroll 1
      for (int i = 0; i < m; ++i) {
        ull b = __ballot(haveslot && !isrem && (myk > nkk[i]));
        if (lane == 0 && b) atomicAdd(&nkc[i], (int)__popcll(b));
      }
      if (haveslot && !isrem) {
        int nb_ = 0;
#pragma unroll 1
        for (int i = 0; i < m; ++i) nb_ += (nkk[i] > myk) ? 1 : 0;
        int np = j - rb_ + nb_;
        Ln[np] = myk;
        if (myk != 0ull) {
          unsigned f = 0xFFFFFFFFu - (unsigned)myk;
          int rr = (int)(f / (unsigned)NC);
          P[rr] = (unsigned short)np;
        }
      }
      __syncthreads(); // B5: nkc complete, live writes done
      if (j < m) {
        ull ki = nkk[j]; int gt = 0;
#pragma unroll 1
        for (int i = 0; i < m; ++i) gt += (nkk[i] > ki) ? 1 : 0;
        int np = base + nkc[j] + gt;
        Ln[np] = ki;
        P[nkr[j]] = (unsigned short)np;
      }
      __syncthreads(); // B6
      flip ^= 1;
    } else {
      // ---- overflow fallback: exact full resort of live keys (retired=sentinel 0) ----
      fullsort(retired ? 0ull : enc(rowmax, argcls));
      flip = 0;
      base = 0;
    }
  }

  // ================== endgame (value exhaustion; exact recon + argmax loop) ==================
  if (ncom < NB) {
    unsigned msk[5] = {0, 0, 0, 0, 0};
    int post_min = INT_MAX;
    bool ret = false; int ccls = commitcls;
    for (int q = 0; q < logcnt; ++q) {
      unsigned e = slog[q];
      int r = (int)(e >> 8), c = (int)(e & 255u);
      if (j == r) { ret = true; ccls = c; post_min = INT_MAX; }
      else {
        if (overlap_ge(bload(c, r), bload(c, j))) {
          if (ret) post_min = (c < post_min) ? c : post_min;
          else {
#pragma unroll
            for (int k5b = 0; k5b < 5; ++k5b) if (k5b == (c >> 5)) msk[k5b] |= (1u << (c & 31));
          }
        }
      }
    }
    retired = ret; if (ret) commitcls = ccls;
    if (retired) {
      rowmax = (post_min != INT_MAX) ? 0.0f : -1.0f;
      argcls = (post_min != INT_MAX) ? post_min : 0;
    } else {
      float bm = -3.4e38f; int ba = 0;
      if (FAST) {
        for (int c4 = 0; c4 < PST / 4; ++c4) {
          float4 v4 = *(const float4*)(xr + c4 * 4);
          int c = c4 * 4;
          float vals[4] = {v4.x, v4.y, v4.z, v4.w};
#pragma unroll
          for (int u = 0; u < 4; ++u) {
            int cc = c + u;
            float v = mbit(msk, cc) ? 0.f : vals[u];
            if (v > bm) { bm = v; ba = cc; }
          }
        }
      } else {
        for (int c = 0; c < NC; ++c) {
          float v;
          if (c == 0) v = 0.f;
          else v = mbit(msk, c) ? 0.f : (expf(xr[c] - m_) / s_);
          if (v > bm) { bm = v; ba = c; }
        }
      }
      rowmax = bm; argcls = ba;
    }

    while (ncom < NB) {
      ull k = enc(rowmax, argcls);
#pragma unroll
      for (int dd = 32; dd >= 1; dd >>= 1) {
        ull o = shflx_u64(k, dd);
        k = k > o ? k : o;
      }
      __syncthreads();
      if (lane == 0) sred[w] = k;
      if (w == 7) {
        volatile int* pb = (volatile int*)slog;    // endgame probe: 1 read/iter
        int t0 = pb[(lane & 31) * 16];
        asm volatile("" :: "v"(t0));
      }
      __syncthreads();
      ull g = sred[0];
#pragma unroll
      for (int q = 1; q < 8; ++q) { ull t = sred[q]; g = g > t ? g : t; }
      unsigned f = 0xFFFFFFFFu - (unsigned)g;
      int row = (int)(f / (unsigned)NC);
      int cls = (int)(f - (unsigned)row * (unsigned)NC);
      float4 cb = bload(cls, row);
      float4 ob = bload(cls, j);
      if (j == row) {
        retired = true; commitcls = cls; post_min = INT_MAX;
        rowmax = -1.0f; argcls = 0;
      } else if (overlap_ge(cb, ob)) {
        if (retired) {
          post_min = (cls < post_min) ? cls : post_min;   // resurrect -1 -> 0.0 @ min cls
          rowmax = 0.0f; argcls = post_min;
        }
        // live rows here are all-zero rows: another 0.0 entry never moves their argmax
      }
      ++ncom;
    }
  }

  commits[j] = (float)commitcls;
}

extern "C" void kernel_launch(void* const* d_in, const int* in_sizes, int n_in,
                              void* d_out, int out_size, void* d_ws, size_t ws_size,
                              hipStream_t stream) {
  const float* A     = (const float*)d_in[0];   // obj_fmap [512,4096]
  const float* boxes = (const float*)d_in[1];   // boxes_per_cls [512,151,4]
  const float* W     = (const float*)d_in[2];   // [4096,151]
  const float* bias  = (const float*)d_in[3];   // [151]
  float* out = (float*)d_out;                   // [512*151] obj_dists ++ [512] commits

  const size_t np = (size_t)KS * NB * PST;      // part
  const size_t nl = (size_t)NB * PST;           // lp
  const size_t nt = (size_t)NB * (2 * NL);      // tl
  const size_t nb = (size_t)NC * NB * 4;        // bt
  const size_t need = (np + nl + nt + nb) * 4;

  if (ws_size >= need) {
    float* part = (float*)d_ws;
    float* lp   = part + np;
    float* tl   = lp + nl;
    float* bt   = tl + nt;
    gemm_fused<<<TPB_GEMM + NTR, 192, 0, stream>>>(A, W, boxes, part, bt);
    prep_kernel<<<NB, 64, 0, stream>>>(part, bias, out, lp, tl);
    decode_kernel<true><<<1, NB, 0, stream>>>(lp, tl, bt, out + NB * NC);
  } else {
    gemm_full<<<NB / 4, 192, 0, stream>>>(A, W, bias, out);
    decode_kernel<false><<<1, NB, 0, stream>>>(out, nullptr, boxes, out + NB * NC);
  }
}